// Round 1
// baseline (3181.248 us; speedup 1.0000x reference)
//
#include <hip/hip_runtime.h>
#include <hip/hip_bf16.h>

// dims (compile-time)
#define S 512
#define N 256
#define CM 64
#define CZ 128
#define CH 32
#define H 8
#define DH 32
#define FF 256
#define HDH 256   // H*DH

__device__ __forceinline__ float waveReduceSum(float v) {
    #pragma unroll
    for (int off = 32; off > 0; off >>= 1) v += __shfl_xor(v, off);
    return v;
}
__device__ __forceinline__ float waveReduceMax(float v) {
    #pragma unroll
    for (int off = 32; off > 0; off >>= 1) v = fmaxf(v, __shfl_xor(v, off));
    return v;
}

// ---------------- K1: OPM layernorm + a/b projections ----------------
// block = 256 threads = 4 rows (wave per row). a,b: (S*N, 32)
__global__ __launch_bounds__(256) void k1_ab(
    const float* __restrict__ m, const float* __restrict__ mask,
    const float* __restrict__ lnw, const float* __restrict__ lnb,
    const float* __restrict__ w1, const float* __restrict__ w2,
    float* __restrict__ a, float* __restrict__ b) {
    __shared__ float mnL[4][64];
    int tid = threadIdx.x, w = tid >> 6, lane = tid & 63;
    int row = blockIdx.x * 4 + w;
    float x = m[row * 64 + lane];
    float mu = waveReduceSum(x) * (1.0f / 64.0f);
    float d = x - mu;
    float var = waveReduceSum(d * d) * (1.0f / 64.0f);
    float rstd = rsqrtf(var + 1e-5f);
    mnL[w][lane] = d * rstd * lnw[lane] + lnb[lane];
    __syncthreads();
    int e = lane & 31;
    const float* W = (lane < 32) ? w1 : w2;
    float acc = 0.f;
    #pragma unroll
    for (int c = 0; c < 64; ++c) acc += mnL[w][c] * W[c * 32 + e];
    float mk = mask[row];
    float* dst = (lane < 32) ? a : b;
    dst[row * 32 + e] = acc * mk;
}

// ---------------- K1b: norm[i,j] = sum_s mask[s,i]*mask[s,j] ----------------
__global__ __launch_bounds__(256) void k1b_norm(
    const float* __restrict__ mask, float* __restrict__ normb) {
    __shared__ float mcol[512];
    int i = blockIdx.x, t = threadIdx.x;
    mcol[t] = mask[t * 256 + i];
    mcol[t + 256] = mask[(t + 256) * 256 + i];
    __syncthreads();
    float acc = 0.f;
    for (int s = 0; s < 512; ++s) acc += mcol[s] * mask[s * 256 + t];
    normb[i * 256 + t] = acc;
}

// ---------------- K2: OPM GEMM (outer = a^T b) + fused wout projection ----------------
// M = N_total = 8192 (i*32+c), K = 512.  64x64 tile per block, 256 threads, 4x4 acc.
// Epilogue: tile = 2x2 (i,j) pairs of full 32x32 (c,e); project each 1024-vec by wout.
__global__ __launch_bounds__(256) void k2_opm(
    const float* __restrict__ a, const float* __restrict__ b,
    const float* __restrict__ wout, const float* __restrict__ bout,
    const float* __restrict__ normb, const float* __restrict__ zin,
    float* __restrict__ zout) {
    __shared__ float lds[64 * 65];
    float* As = lds;            // [16][64]
    float* Bs = lds + 1024;     // [16][64]
    int tid = threadIdx.x;
    int bm = blockIdx.x >> 7, bn = blockIdx.x & 127;
    int m0 = bm * 64, n0 = bn * 64;
    int tx = tid & 15, ty = tid >> 4;
    int lkk = tid >> 4;               // staging row 0..15
    int lcol = (tid & 15) * 4;        // staging col
    float acc[4][4] = {};
    for (int k0 = 0; k0 < 512; k0 += 16) {
        __syncthreads();
        *(float4*)&As[lkk * 64 + lcol] = *(const float4*)&a[(k0 + lkk) * 8192 + m0 + lcol];
        *(float4*)&Bs[lkk * 64 + lcol] = *(const float4*)&b[(k0 + lkk) * 8192 + n0 + lcol];
        __syncthreads();
        #pragma unroll
        for (int kk = 0; kk < 16; ++kk) {
            float4 av = *(float4*)&As[kk * 64 + ty * 4];
            float4 bv = *(float4*)&Bs[kk * 64 + tx * 4];
            acc[0][0] += av.x * bv.x; acc[0][1] += av.x * bv.y; acc[0][2] += av.x * bv.z; acc[0][3] += av.x * bv.w;
            acc[1][0] += av.y * bv.x; acc[1][1] += av.y * bv.y; acc[1][2] += av.y * bv.z; acc[1][3] += av.y * bv.w;
            acc[2][0] += av.z * bv.x; acc[2][1] += av.z * bv.y; acc[2][2] += av.z * bv.z; acc[2][3] += av.z * bv.w;
            acc[3][0] += av.w * bv.x; acc[3][1] += av.w * bv.y; acc[3][2] += av.w * bv.z; acc[3][3] += av.w * bv.w;
        }
    }
    __syncthreads();
    // dump tile to LDS (padded stride 65)
    #pragma unroll
    for (int i = 0; i < 4; ++i)
        #pragma unroll
        for (int j = 0; j < 4; ++j)
            lds[(ty * 4 + i) * 65 + tx * 4 + j] = acc[i][j];
    __syncthreads();
    // epilogue: 4 (i,j)-pairs x 128 f = 512 outputs; 2 per thread
    int f = tid & 127;
    int p0 = tid >> 7;  // pj
    const float* C0 = &lds[0 * 65 + p0 * 32];          // pi=0
    const float* C1 = &lds[32 * 65 + p0 * 32];         // pi=1
    float dot0 = 0.f, dot1 = 0.f;
    for (int c = 0; c < 32; ++c) {
        #pragma unroll
        for (int e = 0; e < 32; ++e) {
            float wv_ = wout[(c * 32 + e) * 128 + f];
            dot0 += C0[c * 65 + e] * wv_;
            dot1 += C1[c * 65 + e] * wv_;
        }
    }
    float bo = bout[f];
    int ig = bm * 2, jg = bn * 2 + p0;
    int ij0 = ig * 256 + jg;
    int ij1 = (ig + 1) * 256 + jg;
    zout[ij0 * 128 + f] = zin[ij0 * 128 + f] + (dot0 + bo) / (normb[ij0] + 1e-3f);
    zout[ij1 * 128 + f] = zin[ij1 * 128 + f] + (dot1 + bo) / (normb[ij1] + 1e-3f);
}

// ---------------- K3: logits[i,h,j] = LN(z_new[i,j,:]) @ wz ----------------
// block = 256 threads = 4 (i,j) pairs (wave per pair)
__global__ __launch_bounds__(256) void k3_logits(
    const float* __restrict__ zout, const float* __restrict__ lnzw,
    const float* __restrict__ lnzb, const float* __restrict__ wz,
    float* __restrict__ wl) {
    __shared__ float znL[4][128];
    int tid = threadIdx.x, w = tid >> 6, lane = tid & 63;
    int pair = blockIdx.x * 4 + w;
    float z0 = zout[pair * 128 + lane];
    float z1 = zout[pair * 128 + 64 + lane];
    float mu = waveReduceSum(z0 + z1) * (1.0f / 128.0f);
    float d0 = z0 - mu, d1 = z1 - mu;
    float var = waveReduceSum(d0 * d0 + d1 * d1) * (1.0f / 128.0f);
    float rstd = rsqrtf(var + 1e-5f);
    znL[w][lane] = d0 * rstd * lnzw[lane] + lnzb[lane];
    znL[w][lane + 64] = d1 * rstd * lnzw[lane + 64] + lnzb[lane + 64];
    __syncthreads();
    int h = lane >> 3, chunk = lane & 7;
    float p = 0.f;
    #pragma unroll
    for (int cc = 0; cc < 16; ++cc) {
        int c = chunk * 16 + cc;
        p += znL[w][c] * wz[c * 8 + h];
    }
    p += __shfl_xor(p, 1); p += __shfl_xor(p, 2); p += __shfl_xor(p, 4);
    if (chunk == 0) {
        int i = pair >> 8, j = pair & 255;
        wl[(i * 8 + h) * 256 + j] = p;
    }
}

// ---------------- K4: softmax over j for each (i,h) row, in place ----------------
__global__ __launch_bounds__(256) void k4_softmax(float* __restrict__ wl) {
    __shared__ float red[8];
    int row = blockIdx.x, t = threadIdx.x;
    int w = t >> 6, lane = t & 63;
    float v = wl[row * 256 + t];
    float mx = waveReduceMax(v);
    if (lane == 0) red[w] = mx;
    __syncthreads();
    mx = fmaxf(fmaxf(red[0], red[1]), fmaxf(red[2], red[3]));
    float ex = expf(v - mx);
    float sm = waveReduceSum(ex);
    if (lane == 0) red[4 + w] = sm;
    __syncthreads();
    float tot = red[4] + red[5] + red[6] + red[7];
    wl[row * 256 + t] = ex / tot;
}

// ---------------- K5: v = LN(m) @ wv  (bf16 out) ----------------
// block = 256 threads = 4 rows
__global__ __launch_bounds__(256) void k5_v(
    const float* __restrict__ m, const float* __restrict__ lnw,
    const float* __restrict__ lnb, const float* __restrict__ wv,
    __hip_bfloat16* __restrict__ v) {
    __shared__ float mnL[4][64];
    int tid = threadIdx.x, w = tid >> 6, lane = tid & 63;
    int rbase = blockIdx.x * 4;
    int row = rbase + w;
    float x = m[row * 64 + lane];
    float mu = waveReduceSum(x) * (1.0f / 64.0f);
    float d = x - mu;
    float var = waveReduceSum(d * d) * (1.0f / 64.0f);
    float rstd = rsqrtf(var + 1e-5f);
    mnL[w][lane] = d * rstd * lnw[lane] + lnb[lane];
    __syncthreads();
    float acc[4] = {0.f, 0.f, 0.f, 0.f};
    for (int c = 0; c < 64; ++c) {
        float wvc = wv[c * 256 + tid];
        #pragma unroll
        for (int r = 0; r < 4; ++r) acc[r] += mnL[r][c] * wvc;
    }
    #pragma unroll
    for (int r = 0; r < 4; ++r)
        v[(rbase + r) * 256 + tid] = __float2bfloat16(acc[r]);
}

// ---------------- K6: o = watt*v ; g recomputed; mout = m + (g*o)@wo ----------------
// block = (s, 8 i's), 256 threads
__global__ __launch_bounds__(256) void k6_pwa(
    const float* __restrict__ m,
    const float* __restrict__ lnmw, const float* __restrict__ lnmb,
    const float* __restrict__ wg, const float* __restrict__ wo,
    const float* __restrict__ wl, const __hip_bfloat16* __restrict__ v,
    float* __restrict__ mout) {
    __shared__ float wattL[2048];   // also reused for g*o
    __shared__ float mn8[8][64];
    int tid = threadIdx.x, w = tid >> 6, lane = tid & 63;
    int s = blockIdx.x >> 5, bi = blockIdx.x & 31;
    int i0 = bi * 8;
    // Phase A: LN for 8 rows (wave w handles rows 2w, 2w+1)
    #pragma unroll
    for (int rr = 0; rr < 2; ++rr) {
        int r = w * 2 + rr;
        int row = s * 256 + i0 + r;
        float x = m[row * 64 + lane];
        float mu = waveReduceSum(x) * (1.0f / 64.0f);
        float d = x - mu;
        float var = waveReduceSum(d * d) * (1.0f / 64.0f);
        float rstd = rsqrtf(var + 1e-5f);
        mn8[r][lane] = d * rstd * lnmw[lane] + lnmb[lane];
    }
    __syncthreads();
    // Phase B: gate for this thread's column across 8 rows
    float gacc[8] = {};
    for (int c = 0; c < 64; ++c) {
        float wgc = wg[c * 256 + tid];
        #pragma unroll
        for (int i = 0; i < 8; ++i) gacc[i] += mn8[i][c] * wgc;
    }
    #pragma unroll
    for (int i = 0; i < 8; ++i) gacc[i] = 1.0f / (1.0f + expf(-gacc[i]));
    // Phase C: o accumulation over j
    float oacc[8] = {};
    int h = tid >> 5;
    for (int jc = 0; jc < 8; ++jc) {
        __syncthreads();
        #pragma unroll
        for (int k = 0; k < 8; ++k) {
            int l = tid + k * 256;
            int il = l >> 8, hl = (l >> 5) & 7, jj = l & 31;
            wattL[l] = wl[((i0 + il) * 8 + hl) * 256 + jc * 32 + jj];
        }
        __syncthreads();
        for (int jj = 0; jj < 32; ++jj) {
            float vv = __bfloat162float(v[(s * 256 + jc * 32 + jj) * 256 + tid]);
            #pragma unroll
            for (int i = 0; i < 8; ++i) oacc[i] += wattL[(i * 8 + h) * 32 + jj] * vv;
        }
    }
    __syncthreads();
    // Phase D: g*o into LDS
    #pragma unroll
    for (int i = 0; i < 8; ++i) wattL[i * 256 + tid] = gacc[i] * oacc[i];
    __syncthreads();
    // Phase E: output projection + residual
    int c = tid & 63;
    int ia = tid >> 6;  // 0..3 ; also handles ia+4
    float acc0 = 0.f, acc1 = 0.f;
    for (int k = 0; k < 256; ++k) {
        float wv_ = wo[k * 64 + c];
        acc0 += wattL[ia * 256 + k] * wv_;
        acc1 += wattL[(ia + 4) * 256 + k] * wv_;
    }
    int row0 = s * 256 + i0 + ia;
    int row1 = row0 + 4;
    mout[row0 * 64 + c] = m[row0 * 64 + c] + acc0;
    mout[row1 * 64 + c] = m[row1 * 64 + c] + acc1;
}

// ---------------- K7: transition (SwiGLU), in-place on mout ----------------
// block = 256 threads = 4 rows
__global__ __launch_bounds__(256) void k7_trans(
    float* __restrict__ mbuf, const float* __restrict__ lnw,
    const float* __restrict__ lnb, const float* __restrict__ wa,
    const float* __restrict__ wb, const float* __restrict__ wo2) {
    __shared__ float xn[4][64];
    __shared__ float hL[4 * 256];
    int tid = threadIdx.x, w = tid >> 6, lane = tid & 63;
    int rbase = blockIdx.x * 4;
    int row = rbase + w;
    float x = mbuf[row * 64 + lane];
    float m_orig = x;
    float mu = waveReduceSum(x) * (1.0f / 64.0f);
    float d = x - mu;
    float var = waveReduceSum(d * d) * (1.0f / 64.0f);
    float rstd = rsqrtf(var + 1e-5f);
    xn[w][lane] = d * rstd * lnw[lane] + lnb[lane];
    __syncthreads();
    float accA[4] = {}, accB[4] = {};
    for (int c = 0; c < 64; ++c) {
        float wac = wa[c * 256 + tid];
        float wbc = wb[c * 256 + tid];
        #pragma unroll
        for (int r = 0; r < 4; ++r) {
            accA[r] += xn[r][c] * wac;
            accB[r] += xn[r][c] * wbc;
        }
    }
    #pragma unroll
    for (int r = 0; r < 4; ++r) {
        float aa = accA[r];
        float sw = aa / (1.0f + expf(-aa));
        hL[r * 256 + tid] = sw * accB[r];
    }
    __syncthreads();
    float acc = 0.f;
    for (int k = 0; k < 256; ++k) acc += hL[w * 256 + k] * wo2[k * 64 + lane];
    mbuf[row * 64 + lane] = m_orig + acc;
}

extern "C" void kernel_launch(void* const* d_in, const int* in_sizes, int n_in,
                              void* d_out, int out_size, void* d_ws, size_t ws_size,
                              hipStream_t stream) {
    const float* m        = (const float*)d_in[0];
    const float* z        = (const float*)d_in[1];
    const float* mask     = (const float*)d_in[2];
    const float* opm_ln_w = (const float*)d_in[3];
    const float* opm_ln_b = (const float*)d_in[4];
    const float* opm_w1   = (const float*)d_in[5];
    const float* opm_w2   = (const float*)d_in[6];
    const float* opm_wout = (const float*)d_in[7];
    const float* opm_bout = (const float*)d_in[8];
    const float* pwa_lnm_w = (const float*)d_in[9];
    const float* pwa_lnm_b = (const float*)d_in[10];
    const float* pwa_lnz_w = (const float*)d_in[11];
    const float* pwa_lnz_b = (const float*)d_in[12];
    const float* pwa_wv   = (const float*)d_in[13];
    const float* pwa_wz   = (const float*)d_in[14];
    const float* pwa_wg   = (const float*)d_in[15];
    const float* pwa_wo   = (const float*)d_in[16];
    const float* tr_ln_w  = (const float*)d_in[17];
    const float* tr_ln_b  = (const float*)d_in[18];
    const float* tr_wa    = (const float*)d_in[19];
    const float* tr_wb    = (const float*)d_in[20];
    const float* tr_wo    = (const float*)d_in[21];

    float* m_out = (float*)d_out;                  // (S*N, 64)
    float* z_out = m_out + (size_t)S * N * CM;     // (N*N, 128)

    // workspace layout (total ~98.3 MB)
    float* a    = (float*)d_ws;                    // 4194304 f
    float* b    = a + 4194304;                     // 4194304 f
    float* normb = b + 4194304;                    // 65536 f
    float* wl   = normb + 65536;                   // 524288 f
    __hip_bfloat16* v = (__hip_bfloat16*)(wl + 524288);  // 33554432 bf16

    k1_ab<<<S * N / 4, 256, 0, stream>>>(m, mask, opm_ln_w, opm_ln_b, opm_w1, opm_w2, a, b);
    k1b_norm<<<N, 256, 0, stream>>>(mask, normb);
    k2_opm<<<128 * 128, 256, 0, stream>>>(a, b, opm_wout, opm_bout, normb, z, z_out);
    k3_logits<<<N * N / 4, 256, 0, stream>>>(z_out, pwa_lnz_w, pwa_lnz_b, pwa_wz, wl);
    k4_softmax<<<N * H, 256, 0, stream>>>(wl);
    k5_v<<<S * N / 4, 256, 0, stream>>>(m, pwa_lnm_w, pwa_lnm_b, pwa_wv, v);
    k6_pwa<<<S * (N / 8), 256, 0, stream>>>(m, pwa_lnm_w, pwa_lnm_b, pwa_wg, pwa_wo, wl, v, m_out);
    k7_trans<<<S * N / 4, 256, 0, stream>>>(m_out, tr_ln_w, tr_ln_b, tr_wa, tr_wb, tr_wo);
}

// Round 2
// 1995.388 us; speedup vs baseline: 1.5943x; 1.5943x over previous
//
#include <hip/hip_runtime.h>
#include <hip/hip_bf16.h>

// dims (compile-time)
#define S 512
#define N 256
#define CM 64
#define CZ 128
#define CH 32
#define H 8
#define DH 32
#define FF 256
#define HDH 256   // H*DH

typedef __attribute__((ext_vector_type(8))) short bf16x8;
typedef __attribute__((ext_vector_type(4))) float f32x4;

__device__ __forceinline__ float waveReduceSum(float v) {
    #pragma unroll
    for (int off = 32; off > 0; off >>= 1) v += __shfl_xor(v, off);
    return v;
}
__device__ __forceinline__ float waveReduceMax(float v) {
    #pragma unroll
    for (int off = 32; off > 0; off >>= 1) v = fmaxf(v, __shfl_xor(v, off));
    return v;
}
__device__ __forceinline__ unsigned short f2bf(float x) {
    __hip_bfloat16 h = __float2bfloat16(x);
    return *reinterpret_cast<unsigned short*>(&h);
}
__device__ __forceinline__ void gload_lds16(const void* g, void* l) {
    __builtin_amdgcn_global_load_lds(
        (const __attribute__((address_space(1))) unsigned int*)g,
        (__attribute__((address_space(3))) unsigned int*)l, 16, 0, 0);
}

// ---------------- K0: wout (1024x128 f32) -> wout_t (128x1024 bf16) ----------------
__global__ __launch_bounds__(256) void k0_wt(
    const float* __restrict__ wout, __hip_bfloat16* __restrict__ wout_t) {
    int idx = blockIdx.x * 256 + threadIdx.x;   // 131072 total
    int f = idx >> 10, k = idx & 1023;
    wout_t[idx] = __float2bfloat16(wout[k * 128 + f]);
}

// ---------------- K1: OPM layernorm + a/b projections, transposed bf16 out ----------------
// a_t[m][k] with m = i*32+e (8192), k = s (512). Block: one i x 64 s-rows.
__global__ __launch_bounds__(256) void k1_ab(
    const float* __restrict__ m, const float* __restrict__ mask,
    const float* __restrict__ lnw, const float* __restrict__ lnb,
    const float* __restrict__ w1, const float* __restrict__ w2,
    __hip_bfloat16* __restrict__ a_t, __hip_bfloat16* __restrict__ b_t) {
    __shared__ float mn[64][64];
    __shared__ float mk[64];
    int tid = threadIdx.x, w = tid >> 6, lane = tid & 63;
    int i = blockIdx.x >> 3, s0 = (blockIdx.x & 7) * 64;
    float lw = lnw[lane], lb = lnb[lane];
    for (int rr = 0; rr < 16; ++rr) {
        int sl = w * 16 + rr;
        float x = m[((size_t)(s0 + sl) * 256 + i) * 64 + lane];
        float mu = waveReduceSum(x) * (1.0f / 64.0f);
        float d = x - mu;
        float var = waveReduceSum(d * d) * (1.0f / 64.0f);
        mn[sl][lane] = d * rsqrtf(var + 1e-5f) * lw + lb;
        if (lane == 0) mk[sl] = mask[(s0 + sl) * 256 + i];
    }
    __syncthreads();
    int e = lane & 31;
    const float* W = (lane < 32) ? w1 : w2;
    __hip_bfloat16* dst = (lane < 32) ? a_t : b_t;
    float acc[16];
    #pragma unroll
    for (int ss = 0; ss < 16; ++ss) acc[ss] = 0.f;
    for (int c = 0; c < 64; ++c) {
        float wc = W[c * 32 + e];
        #pragma unroll
        for (int ss = 0; ss < 16; ++ss)
            acc[ss] += mn[w * 16 + ss][c] * wc;
    }
    __hip_bfloat16 outv[16];
    #pragma unroll
    for (int ss = 0; ss < 16; ++ss)
        outv[ss] = __float2bfloat16(acc[ss] * mk[w * 16 + ss]);
    __hip_bfloat16* p = dst + (size_t)(i * 32 + e) * 512 + s0 + w * 16;
    *(bf16x8*)p = *(bf16x8*)&outv[0];
    *(bf16x8*)(p + 8) = *(bf16x8*)&outv[8];
}

// ---------------- K1b: norm[i,j] = sum_s mask[s,i]*mask[s,j] ----------------
__global__ __launch_bounds__(256) void k1b_norm(
    const float* __restrict__ mask, float* __restrict__ normb) {
    __shared__ float mcol[512];
    int i = blockIdx.x, t = threadIdx.x;
    mcol[t] = mask[t * 256 + i];
    mcol[t + 256] = mask[(t + 256) * 256 + i];
    __syncthreads();
    float acc = 0.f;
    for (int s = 0; s < 512; ++s) acc += mcol[s] * mask[s * 256 + t];
    normb[i * 256 + t] = acc;
}

// ---------------- K2: OPM bf16 MFMA GEMM + fused MFMA wout projection ----------------
// Stage 1: outer 128x128 tile = a_t[m][k] . b_t[n][k]^T over K=512.
// Stage 2: per (i,j) pair (16 per block), D[pair][f] = Cp[pair][1024] @ wout_t^T.
__global__ __launch_bounds__(256) void k2_opm(
    const __hip_bfloat16* __restrict__ a_t, const __hip_bfloat16* __restrict__ b_t,
    const __hip_bfloat16* __restrict__ wout_t, const float* __restrict__ bout,
    const float* __restrict__ normb, const float* __restrict__ zin,
    float* __restrict__ zout) {
    __shared__ __align__(16) char smem[32768];
    char* As = smem;            // [128][32] bf16, source pre-swizzled
    char* Bs = smem + 8192;
    int tid = threadIdx.x;
    int wid = tid >> 6, lane = tid & 63;
    int g = lane >> 4, lc = lane & 15;
    int bm = blockIdx.x >> 6, bn = blockIdx.x & 63;
    int m0 = bm * 128, n0 = bn * 128;
    int wm = wid >> 1, wn = wid & 1;

    f32x4 acc[4][4];
    #pragma unroll
    for (int fm = 0; fm < 4; ++fm)
        #pragma unroll
        for (int fn = 0; fn < 4; ++fn)
            acc[fm][fn] = (f32x4){0.f, 0.f, 0.f, 0.f};

    for (int k0 = 0; k0 < 512; k0 += 32) {
        __syncthreads();
        #pragma unroll
        for (int h = 0; h < 2; ++h) {
            int c = h * 256 + wid * 64 + lane;
            int r = c >> 2, gs = c & 3;
            int gk = gs ^ ((r >> 1) & 3);          // pre-swizzled source chunk
            const __hip_bfloat16* ga = a_t + (size_t)(m0 + r) * 512 + k0 + gk * 8;
            const __hip_bfloat16* gb = b_t + (size_t)(n0 + r) * 512 + k0 + gk * 8;
            gload_lds16(ga, As + h * 4096 + wid * 1024);
            gload_lds16(gb, Bs + h * 4096 + wid * 1024);
        }
        __syncthreads();
        bf16x8 af[4], bfr[4];
        #pragma unroll
        for (int fm = 0; fm < 4; ++fm) {
            int row = wm * 64 + fm * 16 + lc;
            int sw = (g * 16) ^ (((row >> 1) & 3) << 4);
            af[fm] = *(bf16x8*)(As + row * 64 + sw);
        }
        #pragma unroll
        for (int fn = 0; fn < 4; ++fn) {
            int row = wn * 64 + fn * 16 + lc;
            int sw = (g * 16) ^ (((row >> 1) & 3) << 4);
            bfr[fn] = *(bf16x8*)(Bs + row * 64 + sw);
        }
        #pragma unroll
        for (int fm = 0; fm < 4; ++fm)
            #pragma unroll
            for (int fn = 0; fn < 4; ++fn)
                acc[fm][fn] = __builtin_amdgcn_mfma_f32_16x16x32_bf16(
                    af[fm], bfr[fn], acc[fm][fn], 0, 0, 0);
    }
    __syncthreads();
    // ---- dump accumulators to Cp[pair][1024] bf16 (swizzled) ----
    #pragma unroll
    for (int fm = 0; fm < 4; ++fm) {
        int i_loc = wm * 2 + (fm >> 1);
        #pragma unroll
        for (int fn = 0; fn < 4; ++fn) {
            int j_loc = wn * 2 + (fn >> 1);
            int pair = i_loc * 4 + j_loc;
            int xorp = (pair & 7) << 4;
            #pragma unroll
            for (int r = 0; r < 4; ++r) {
                int mm31 = (fm & 1) * 16 + g * 4 + r;
                int nn31 = (fn & 1) * 16 + lc;
                int off = mm31 * 64 + nn31 * 2;
                int offs = off ^ xorp ^ (((off >> 8) & 3) << 4);
                *(unsigned short*)(smem + pair * 2048 + offs) = f2bf(acc[fm][fn][r]);
            }
        }
    }
    __syncthreads();
    // ---- stage 2: D[pair][f] = Cp @ wout ----
    f32x4 acc2[2];
    acc2[0] = (f32x4){0.f, 0.f, 0.f, 0.f};
    acc2[1] = (f32x4){0.f, 0.f, 0.f, 0.f};
    int f0 = wid * 32;
    int pr = lc;
    int xorp2 = (pr & 7) << 4;
    for (int k2 = 0; k2 < 1024; k2 += 32) {
        int offA = k2 * 2 + g * 16;
        int offAs = offA ^ xorp2 ^ (((offA >> 8) & 3) << 4);
        bf16x8 af2 = *(bf16x8*)(smem + pr * 2048 + offAs);
        #pragma unroll
        for (int fn2 = 0; fn2 < 2; ++fn2) {
            int f = f0 + fn2 * 16 + lc;
            bf16x8 bw = *(const bf16x8*)(wout_t + (size_t)f * 1024 + k2 + g * 8);
            acc2[fn2] = __builtin_amdgcn_mfma_f32_16x16x32_bf16(af2, bw, acc2[fn2], 0, 0, 0);
        }
    }
    // ---- epilogue: bias, /(norm+eps), residual ----
    #pragma unroll
    for (int fn2 = 0; fn2 < 2; ++fn2) {
        #pragma unroll
        for (int r = 0; r < 4; ++r) {
            int pair = g * 4 + r;
            int i = bm * 4 + (pair >> 2), j = bn * 4 + (pair & 3);
            int ij = i * 256 + j;
            int f = f0 + fn2 * 16 + lc;
            float d = acc2[fn2][r];
            zout[(size_t)ij * 128 + f] = zin[(size_t)ij * 128 + f] +
                (d + bout[f]) / (normb[ij] + 1e-3f);
        }
    }
}

// ---------------- K3: logits[i,h,j] = LN(z_new[i,j,:]) @ wz ----------------
__global__ __launch_bounds__(256) void k3_logits(
    const float* __restrict__ zout, const float* __restrict__ lnzw,
    const float* __restrict__ lnzb, const float* __restrict__ wz,
    float* __restrict__ wl) {
    __shared__ float znL[4][128];
    int tid = threadIdx.x, w = tid >> 6, lane = tid & 63;
    int pair = blockIdx.x * 4 + w;
    float z0 = zout[pair * 128 + lane];
    float z1 = zout[pair * 128 + 64 + lane];
    float mu = waveReduceSum(z0 + z1) * (1.0f / 128.0f);
    float d0 = z0 - mu, d1 = z1 - mu;
    float var = waveReduceSum(d0 * d0 + d1 * d1) * (1.0f / 128.0f);
    float rstd = rsqrtf(var + 1e-5f);
    znL[w][lane] = d0 * rstd * lnzw[lane] + lnzb[lane];
    znL[w][lane + 64] = d1 * rstd * lnzw[lane + 64] + lnzb[lane + 64];
    __syncthreads();
    int h = lane >> 3, chunk = lane & 7;
    float p = 0.f;
    #pragma unroll
    for (int cc = 0; cc < 16; ++cc) {
        int c = chunk * 16 + cc;
        p += znL[w][c] * wz[c * 8 + h];
    }
    p += __shfl_xor(p, 1); p += __shfl_xor(p, 2); p += __shfl_xor(p, 4);
    if (chunk == 0) {
        int i = pair >> 8, j = pair & 255;
        wl[(i * 8 + h) * 256 + j] = p;
    }
}

// ---------------- K4: softmax over j for each (i,h) row, in place ----------------
__global__ __launch_bounds__(256) void k4_softmax(float* __restrict__ wl) {
    __shared__ float red[8];
    int row = blockIdx.x, t = threadIdx.x;
    int w = t >> 6, lane = t & 63;
    float v = wl[row * 256 + t];
    float mx = waveReduceMax(v);
    if (lane == 0) red[w] = mx;
    __syncthreads();
    mx = fmaxf(fmaxf(red[0], red[1]), fmaxf(red[2], red[3]));
    float ex = expf(v - mx);
    float sm = waveReduceSum(ex);
    if (lane == 0) red[4 + w] = sm;
    __syncthreads();
    float tot = red[4] + red[5] + red[6] + red[7];
    wl[row * 256 + t] = ex / tot;
}

// ---------------- K5: v = LN(m) @ wv  (bf16 out) ----------------
__global__ __launch_bounds__(256) void k5_v(
    const float* __restrict__ m, const float* __restrict__ lnw,
    const float* __restrict__ lnb, const float* __restrict__ wv,
    __hip_bfloat16* __restrict__ v) {
    __shared__ float mnL[4][64];
    int tid = threadIdx.x, w = tid >> 6, lane = tid & 63;
    int rbase = blockIdx.x * 4;
    int row = rbase + w;
    float x = m[row * 64 + lane];
    float mu = waveReduceSum(x) * (1.0f / 64.0f);
    float d = x - mu;
    float var = waveReduceSum(d * d) * (1.0f / 64.0f);
    float rstd = rsqrtf(var + 1e-5f);
    mnL[w][lane] = d * rstd * lnw[lane] + lnb[lane];
    __syncthreads();
    float acc[4] = {0.f, 0.f, 0.f, 0.f};
    for (int c = 0; c < 64; ++c) {
        float wvc = wv[c * 256 + tid];
        #pragma unroll
        for (int r = 0; r < 4; ++r) acc[r] += mnL[r][c] * wvc;
    }
    #pragma unroll
    for (int r = 0; r < 4; ++r)
        v[(rbase + r) * 256 + tid] = __float2bfloat16(acc[r]);
}

// ---------------- K6: o = watt*v ; g recomputed; mout = m + (g*o)@wo ----------------
__global__ __launch_bounds__(256) void k6_pwa(
    const float* __restrict__ m,
    const float* __restrict__ lnmw, const float* __restrict__ lnmb,
    const float* __restrict__ wg, const float* __restrict__ wo,
    const float* __restrict__ wl, const __hip_bfloat16* __restrict__ v,
    float* __restrict__ mout) {
    __shared__ float wattL[2048];   // also reused for g*o
    __shared__ float mn8[8][64];
    int tid = threadIdx.x, w = tid >> 6, lane = tid & 63;
    int s = blockIdx.x >> 5, bi = blockIdx.x & 31;
    int i0 = bi * 8;
    #pragma unroll
    for (int rr = 0; rr < 2; ++rr) {
        int r = w * 2 + rr;
        int row = s * 256 + i0 + r;
        float x = m[row * 64 + lane];
        float mu = waveReduceSum(x) * (1.0f / 64.0f);
        float d = x - mu;
        float var = waveReduceSum(d * d) * (1.0f / 64.0f);
        float rstd = rsqrtf(var + 1e-5f);
        mn8[r][lane] = d * rstd * lnmw[lane] + lnmb[lane];
    }
    __syncthreads();
    float gacc[8] = {};
    for (int c = 0; c < 64; ++c) {
        float wgc = wg[c * 256 + tid];
        #pragma unroll
        for (int i = 0; i < 8; ++i) gacc[i] += mn8[i][c] * wgc;
    }
    #pragma unroll
    for (int i = 0; i < 8; ++i) gacc[i] = 1.0f / (1.0f + expf(-gacc[i]));
    float oacc[8] = {};
    int h = tid >> 5;
    for (int jc = 0; jc < 8; ++jc) {
        __syncthreads();
        #pragma unroll
        for (int k = 0; k < 8; ++k) {
            int l = tid + k * 256;
            int il = l >> 8, hl = (l >> 5) & 7, jj = l & 31;
            wattL[l] = wl[((i0 + il) * 8 + hl) * 256 + jc * 32 + jj];
        }
        __syncthreads();
        for (int jj = 0; jj < 32; ++jj) {
            float vv = __bfloat162float(v[(s * 256 + jc * 32 + jj) * 256 + tid]);
            #pragma unroll
            for (int i = 0; i < 8; ++i) oacc[i] += wattL[(i * 8 + h) * 32 + jj] * vv;
        }
    }
    __syncthreads();
    #pragma unroll
    for (int i = 0; i < 8; ++i) wattL[i * 256 + tid] = gacc[i] * oacc[i];
    __syncthreads();
    int c = tid & 63;
    int ia = tid >> 6;
    float acc0 = 0.f, acc1 = 0.f;
    for (int k = 0; k < 256; ++k) {
        float wv_ = wo[k * 64 + c];
        acc0 += wattL[ia * 256 + k] * wv_;
        acc1 += wattL[(ia + 4) * 256 + k] * wv_;
    }
    int row0 = s * 256 + i0 + ia;
    int row1 = row0 + 4;
    mout[row0 * 64 + c] = m[row0 * 64 + c] + acc0;
    mout[row1 * 64 + c] = m[row1 * 64 + c] + acc1;
}

// ---------------- K7: transition (SwiGLU), in-place on mout ----------------
__global__ __launch_bounds__(256) void k7_trans(
    float* __restrict__ mbuf, const float* __restrict__ lnw,
    const float* __restrict__ lnb, const float* __restrict__ wa,
    const float* __restrict__ wb, const float* __restrict__ wo2) {
    __shared__ float xn[4][64];
    __shared__ float hL[4 * 256];
    int tid = threadIdx.x, w = tid >> 6, lane = tid & 63;
    int rbase = blockIdx.x * 4;
    int row = rbase + w;
    float x = mbuf[row * 64 + lane];
    float m_orig = x;
    float mu = waveReduceSum(x) * (1.0f / 64.0f);
    float d = x - mu;
    float var = waveReduceSum(d * d) * (1.0f / 64.0f);
    float rstd = rsqrtf(var + 1e-5f);
    xn[w][lane] = d * rstd * lnw[lane] + lnb[lane];
    __syncthreads();
    float accA[4] = {}, accB[4] = {};
    for (int c = 0; c < 64; ++c) {
        float wac = wa[c * 256 + tid];
        float wbc = wb[c * 256 + tid];
        #pragma unroll
        for (int r = 0; r < 4; ++r) {
            accA[r] += xn[r][c] * wac;
            accB[r] += xn[r][c] * wbc;
        }
    }
    #pragma unroll
    for (int r = 0; r < 4; ++r) {
        float aa = accA[r];
        float sw = aa / (1.0f + expf(-aa));
        hL[r * 256 + tid] = sw * accB[r];
    }
    __syncthreads();
    float acc = 0.f;
    for (int k = 0; k < 256; ++k) acc += hL[w * 256 + k] * wo2[k * 64 + lane];
    mbuf[row * 64 + lane] = m_orig + acc;
}

extern "C" void kernel_launch(void* const* d_in, const int* in_sizes, int n_in,
                              void* d_out, int out_size, void* d_ws, size_t ws_size,
                              hipStream_t stream) {
    const float* m        = (const float*)d_in[0];
    const float* z        = (const float*)d_in[1];
    const float* mask     = (const float*)d_in[2];
    const float* opm_ln_w = (const float*)d_in[3];
    const float* opm_ln_b = (const float*)d_in[4];
    const float* opm_w1   = (const float*)d_in[5];
    const float* opm_w2   = (const float*)d_in[6];
    const float* opm_wout = (const float*)d_in[7];
    const float* opm_bout = (const float*)d_in[8];
    const float* pwa_lnm_w = (const float*)d_in[9];
    const float* pwa_lnm_b = (const float*)d_in[10];
    const float* pwa_lnz_w = (const float*)d_in[11];
    const float* pwa_lnz_b = (const float*)d_in[12];
    const float* pwa_wv   = (const float*)d_in[13];
    const float* pwa_wz   = (const float*)d_in[14];
    const float* pwa_wg   = (const float*)d_in[15];
    const float* pwa_wo   = (const float*)d_in[16];
    const float* tr_ln_w  = (const float*)d_in[17];
    const float* tr_ln_b  = (const float*)d_in[18];
    const float* tr_wa    = (const float*)d_in[19];
    const float* tr_wb    = (const float*)d_in[20];
    const float* tr_wo    = (const float*)d_in[21];

    float* m_out = (float*)d_out;                  // (S*N, 64)
    float* z_out = m_out + (size_t)S * N * CM;     // (N*N, 128)

    // workspace layout (~82.5 MB)
    __hip_bfloat16* a_t    = (__hip_bfloat16*)d_ws;          // 8192x512 bf16
    __hip_bfloat16* b_t    = a_t + 4194304;                  // 8192x512 bf16
    __hip_bfloat16* wout_t = b_t + 4194304;                  // 128x1024 bf16
    float* normb = (float*)(wout_t + 131072);                // 65536 f32
    float* wl    = normb + 65536;                            // 524288 f32
    __hip_bfloat16* v = (__hip_bfloat16*)(wl + 524288);      // 33554432 bf16

    k0_wt<<<512, 256, 0, stream>>>(opm_wout, wout_t);
    k1_ab<<<2048, 256, 0, stream>>>(m, mask, opm_ln_w, opm_ln_b, opm_w1, opm_w2, a_t, b_t);
    k1b_norm<<<N, 256, 0, stream>>>(mask, normb);
    k2_opm<<<4096, 256, 0, stream>>>(a_t, b_t, wout_t, opm_bout, normb, z, z_out);
    k3_logits<<<N * N / 4, 256, 0, stream>>>(z_out, pwa_lnz_w, pwa_lnz_b, pwa_wz, wl);
    k4_softmax<<<N * H, 256, 0, stream>>>(wl);
    k5_v<<<S * N / 4, 256, 0, stream>>>(m, pwa_lnm_w, pwa_lnm_b, pwa_wv, v);
    k6_pwa<<<S * (N / 8), 256, 0, stream>>>(m, pwa_lnm_w, pwa_lnm_b, pwa_wg, pwa_wo, wl, v, m_out);
    k7_trans<<<S * N / 4, 256, 0, stream>>>(m_out, tr_ln_w, tr_ln_b, tr_wa, tr_wb, tr_wo);
}

// Round 3
// 827.026 us; speedup vs baseline: 3.8466x; 2.4127x over previous
//
#include <hip/hip_runtime.h>
#include <hip/hip_bf16.h>

// dims (compile-time)
#define S 512
#define N 256
#define CM 64
#define CZ 128
#define CH 32
#define H 8
#define DH 32
#define FF 256
#define HDH 256   // H*DH

typedef __attribute__((ext_vector_type(8))) short bf16x8;
typedef __attribute__((ext_vector_type(4))) float f32x4;

__device__ __forceinline__ float waveReduceSum(float v) {
    #pragma unroll
    for (int off = 32; off > 0; off >>= 1) v += __shfl_xor(v, off);
    return v;
}
__device__ __forceinline__ float waveReduceMax(float v) {
    #pragma unroll
    for (int off = 32; off > 0; off >>= 1) v = fmaxf(v, __shfl_xor(v, off));
    return v;
}
__device__ __forceinline__ unsigned short f2bf(float x) {
    __hip_bfloat16 h = __float2bfloat16(x);
    return *reinterpret_cast<unsigned short*>(&h);
}
__device__ __forceinline__ float bfbits2f(short u) {
    unsigned int x = ((unsigned int)(unsigned short)u) << 16;
    return __uint_as_float(x);
}
__device__ __forceinline__ void gload_lds16(const void* g, void* l) {
    __builtin_amdgcn_global_load_lds(
        (const __attribute__((address_space(1))) unsigned int*)g,
        (__attribute__((address_space(3))) unsigned int*)l, 16, 0, 0);
}

// ---------------- K0: weight transposes to bf16 ----------------
// wout_t[128][1024], wv_t[256][64], wg_t[256][64], wab_t[512][64],
// wo_t[64][256], wo2_t[64][256]
__global__ __launch_bounds__(256) void k0_prep(
    const float* __restrict__ wout, const float* __restrict__ wv,
    const float* __restrict__ wg, const float* __restrict__ wa,
    const float* __restrict__ wb, const float* __restrict__ wo,
    const float* __restrict__ wo2,
    __hip_bfloat16* __restrict__ wout_t, __hip_bfloat16* __restrict__ wv_t,
    __hip_bfloat16* __restrict__ wg_t, __hip_bfloat16* __restrict__ wab_t,
    __hip_bfloat16* __restrict__ wo_t, __hip_bfloat16* __restrict__ wo2_t) {
    int idx = blockIdx.x * 256 + threadIdx.x;
    if (idx < 131072) {
        int f = idx >> 10, k = idx & 1023;
        wout_t[idx] = __float2bfloat16(wout[k * 128 + f]);
    } else if (idx < 147456) {
        int t = idx - 131072; int n = t >> 6, k = t & 63;
        wv_t[t] = __float2bfloat16(wv[k * 256 + n]);
    } else if (idx < 163840) {
        int t = idx - 147456; int n = t >> 6, k = t & 63;
        wg_t[t] = __float2bfloat16(wg[k * 256 + n]);
    } else if (idx < 196608) {
        int t = idx - 163840; int n = t >> 6, k = t & 63;
        wab_t[t] = __float2bfloat16(n < 256 ? wa[k * 256 + n] : wb[k * 256 + (n - 256)]);
    } else if (idx < 212992) {
        int t = idx - 196608; int n = t >> 8, k = t & 255;
        wo_t[t] = __float2bfloat16(wo[k * 64 + n]);
    } else if (idx < 229376) {
        int t = idx - 212992; int n = t >> 8, k = t & 255;
        wo2_t[t] = __float2bfloat16(wo2[k * 64 + n]);
    }
}

// ---------------- K1: OPM layernorm + a/b projections, transposed bf16 out ----------------
__global__ __launch_bounds__(256) void k1_ab(
    const float* __restrict__ m, const float* __restrict__ mask,
    const float* __restrict__ lnw, const float* __restrict__ lnb,
    const float* __restrict__ w1, const float* __restrict__ w2,
    __hip_bfloat16* __restrict__ a_t, __hip_bfloat16* __restrict__ b_t) {
    __shared__ float mn[64][64];
    __shared__ float mk[64];
    int tid = threadIdx.x, w = tid >> 6, lane = tid & 63;
    int i = blockIdx.x >> 3, s0 = (blockIdx.x & 7) * 64;
    float lw = lnw[lane], lb = lnb[lane];
    for (int rr = 0; rr < 16; ++rr) {
        int sl = w * 16 + rr;
        float x = m[((size_t)(s0 + sl) * 256 + i) * 64 + lane];
        float mu = waveReduceSum(x) * (1.0f / 64.0f);
        float d = x - mu;
        float var = waveReduceSum(d * d) * (1.0f / 64.0f);
        mn[sl][lane] = d * rsqrtf(var + 1e-5f) * lw + lb;
        if (lane == 0) mk[sl] = mask[(s0 + sl) * 256 + i];
    }
    __syncthreads();
    int e = lane & 31;
    const float* W = (lane < 32) ? w1 : w2;
    __hip_bfloat16* dst = (lane < 32) ? a_t : b_t;
    float acc[16];
    #pragma unroll
    for (int ss = 0; ss < 16; ++ss) acc[ss] = 0.f;
    for (int c = 0; c < 64; ++c) {
        float wc = W[c * 32 + e];
        #pragma unroll
        for (int ss = 0; ss < 16; ++ss)
            acc[ss] += mn[w * 16 + ss][c] * wc;
    }
    __hip_bfloat16 outv[16];
    #pragma unroll
    for (int ss = 0; ss < 16; ++ss)
        outv[ss] = __float2bfloat16(acc[ss] * mk[w * 16 + ss]);
    __hip_bfloat16* p = dst + (size_t)(i * 32 + e) * 512 + s0 + w * 16;
    *(bf16x8*)p = *(bf16x8*)&outv[0];
    *(bf16x8*)(p + 8) = *(bf16x8*)&outv[8];
}

// ---------------- K1b: norm[i,j] = sum_s mask[s,i]*mask[s,j] ----------------
__global__ __launch_bounds__(256) void k1b_norm(
    const float* __restrict__ mask, float* __restrict__ normb) {
    __shared__ float mcol[512];
    int i = blockIdx.x, t = threadIdx.x;
    mcol[t] = mask[t * 256 + i];
    mcol[t + 256] = mask[(t + 256) * 256 + i];
    __syncthreads();
    float acc = 0.f;
    for (int s = 0; s < 512; ++s) acc += mcol[s] * mask[s * 256 + t];
    normb[i * 256 + t] = acc;
}

// ---------------- K2: OPM bf16 MFMA GEMM + fused MFMA wout projection ----------------
__global__ __launch_bounds__(256) void k2_opm(
    const __hip_bfloat16* __restrict__ a_t, const __hip_bfloat16* __restrict__ b_t,
    const __hip_bfloat16* __restrict__ wout_t, const float* __restrict__ bout,
    const float* __restrict__ normb, const float* __restrict__ zin,
    float* __restrict__ zout) {
    __shared__ __align__(16) char smem[32768];
    char* As = smem;            // [128][32] bf16, source pre-swizzled
    char* Bs = smem + 8192;
    int tid = threadIdx.x;
    int wid = tid >> 6, lane = tid & 63;
    int g = lane >> 4, lc = lane & 15;
    int bm = blockIdx.x >> 6, bn = blockIdx.x & 63;
    int m0 = bm * 128, n0 = bn * 128;
    int wm = wid >> 1, wn = wid & 1;

    f32x4 acc[4][4];
    #pragma unroll
    for (int fm = 0; fm < 4; ++fm)
        #pragma unroll
        for (int fn = 0; fn < 4; ++fn)
            acc[fm][fn] = (f32x4){0.f, 0.f, 0.f, 0.f};

    for (int k0 = 0; k0 < 512; k0 += 32) {
        __syncthreads();
        #pragma unroll
        for (int h = 0; h < 2; ++h) {
            int c = h * 256 + wid * 64 + lane;
            int r = c >> 2, gs = c & 3;
            int gk = gs ^ ((r >> 1) & 3);
            const __hip_bfloat16* ga = a_t + (size_t)(m0 + r) * 512 + k0 + gk * 8;
            const __hip_bfloat16* gb = b_t + (size_t)(n0 + r) * 512 + k0 + gk * 8;
            gload_lds16(ga, As + h * 4096 + wid * 1024);
            gload_lds16(gb, Bs + h * 4096 + wid * 1024);
        }
        __syncthreads();
        bf16x8 af[4], bfr[4];
        #pragma unroll
        for (int fm = 0; fm < 4; ++fm) {
            int row = wm * 64 + fm * 16 + lc;
            int sw = (g * 16) ^ (((row >> 1) & 3) << 4);
            af[fm] = *(bf16x8*)(As + row * 64 + sw);
        }
        #pragma unroll
        for (int fn = 0; fn < 4; ++fn) {
            int row = wn * 64 + fn * 16 + lc;
            int sw = (g * 16) ^ (((row >> 1) & 3) << 4);
            bfr[fn] = *(bf16x8*)(Bs + row * 64 + sw);
        }
        #pragma unroll
        for (int fm = 0; fm < 4; ++fm)
            #pragma unroll
            for (int fn = 0; fn < 4; ++fn)
                acc[fm][fn] = __builtin_amdgcn_mfma_f32_16x16x32_bf16(
                    af[fm], bfr[fn], acc[fm][fn], 0, 0, 0);
    }
    __syncthreads();
    #pragma unroll
    for (int fm = 0; fm < 4; ++fm) {
        int i_loc = wm * 2 + (fm >> 1);
        #pragma unroll
        for (int fn = 0; fn < 4; ++fn) {
            int j_loc = wn * 2 + (fn >> 1);
            int pair = i_loc * 4 + j_loc;
            int xorp = (pair & 7) << 4;
            #pragma unroll
            for (int r = 0; r < 4; ++r) {
                int mm31 = (fm & 1) * 16 + g * 4 + r;
                int nn31 = (fn & 1) * 16 + lc;
                int off = mm31 * 64 + nn31 * 2;
                int offs = off ^ xorp ^ (((off >> 8) & 3) << 4);
                *(unsigned short*)(smem + pair * 2048 + offs) = f2bf(acc[fm][fn][r]);
            }
        }
    }
    __syncthreads();
    f32x4 acc2[2];
    acc2[0] = (f32x4){0.f, 0.f, 0.f, 0.f};
    acc2[1] = (f32x4){0.f, 0.f, 0.f, 0.f};
    int f0 = wid * 32;
    int pr = lc;
    int xorp2 = (pr & 7) << 4;
    for (int k2 = 0; k2 < 1024; k2 += 32) {
        int offA = k2 * 2 + g * 16;
        int offAs = offA ^ xorp2 ^ (((offA >> 8) & 3) << 4);
        bf16x8 af2 = *(bf16x8*)(smem + pr * 2048 + offAs);
        #pragma unroll
        for (int fn2 = 0; fn2 < 2; ++fn2) {
            int f = f0 + fn2 * 16 + lc;
            bf16x8 bw = *(const bf16x8*)(wout_t + (size_t)f * 1024 + k2 + g * 8);
            acc2[fn2] = __builtin_amdgcn_mfma_f32_16x16x32_bf16(af2, bw, acc2[fn2], 0, 0, 0);
        }
    }
    #pragma unroll
    for (int fn2 = 0; fn2 < 2; ++fn2) {
        #pragma unroll
        for (int r = 0; r < 4; ++r) {
            int pair = g * 4 + r;
            int i = bm * 4 + (pair >> 2), j = bn * 4 + (pair & 3);
            int ij = i * 256 + j;
            int f = f0 + fn2 * 16 + lc;
            float d = acc2[fn2][r];
            zout[(size_t)ij * 128 + f] = zin[(size_t)ij * 128 + f] +
                (d + bout[f]) / (normb[ij] + 1e-3f);
        }
    }
}

// ---------------- K3: logits[i,h,j] = LN(z_new[i,j,:]) @ wz ----------------
__global__ __launch_bounds__(256) void k3_logits(
    const float* __restrict__ zout, const float* __restrict__ lnzw,
    const float* __restrict__ lnzb, const float* __restrict__ wz,
    float* __restrict__ wl) {
    __shared__ float znL[4][128];
    int tid = threadIdx.x, w = tid >> 6, lane = tid & 63;
    int pair = blockIdx.x * 4 + w;
    float z0 = zout[pair * 128 + lane];
    float z1 = zout[pair * 128 + 64 + lane];
    float mu = waveReduceSum(z0 + z1) * (1.0f / 128.0f);
    float d0 = z0 - mu, d1 = z1 - mu;
    float var = waveReduceSum(d0 * d0 + d1 * d1) * (1.0f / 128.0f);
    float rstd = rsqrtf(var + 1e-5f);
    znL[w][lane] = d0 * rstd * lnzw[lane] + lnzb[lane];
    znL[w][lane + 64] = d1 * rstd * lnzw[lane + 64] + lnzb[lane + 64];
    __syncthreads();
    int h = lane >> 3, chunk = lane & 7;
    float p = 0.f;
    #pragma unroll
    for (int cc = 0; cc < 16; ++cc) {
        int c = chunk * 16 + cc;
        p += znL[w][c] * wz[c * 8 + h];
    }
    p += __shfl_xor(p, 1); p += __shfl_xor(p, 2); p += __shfl_xor(p, 4);
    if (chunk == 0) {
        int i = pair >> 8, j = pair & 255;
        wl[(i * 8 + h) * 256 + j] = p;
    }
}

// ---------------- K4: softmax over j; write bf16 wlb[h][i][j] ----------------
__global__ __launch_bounds__(256) void k4_softmax(
    const float* __restrict__ wl, __hip_bfloat16* __restrict__ wlb) {
    __shared__ float red[8];
    int row = blockIdx.x, t = threadIdx.x;   // row = i*8+h
    int w = t >> 6, lane = t & 63;
    float v = wl[row * 256 + t];
    float mx = waveReduceMax(v);
    if (lane == 0) red[w] = mx;
    __syncthreads();
    mx = fmaxf(fmaxf(red[0], red[1]), fmaxf(red[2], red[3]));
    float ex = expf(v - mx);
    float sm = waveReduceSum(ex);
    if (lane == 0) red[4 + w] = sm;
    __syncthreads();
    float tot = red[4] + red[5] + red[6] + red[7];
    int i = row >> 3, h = row & 7;
    wlb[((h << 8) | i) * 256 + t] = __float2bfloat16(ex / tot);
}

// ---------------- K5: fused LN + [64->256] GEMM (mode 0: v scatter; 1: sigmoid g) ----------------
// block = 64 rows, 4 waves (16 rows each over full N=256)
__global__ __launch_bounds__(256) void k5vg(
    const float* __restrict__ m, const float* __restrict__ lnw,
    const float* __restrict__ lnb, const __hip_bfloat16* __restrict__ Bt,
    __hip_bfloat16* __restrict__ out, int mode) {
    __shared__ __align__(16) char As[64 * 128];
    int tid = threadIdx.x, wid = tid >> 6, lane = tid & 63;
    int g = lane >> 4, lc = lane & 15;
    int r0 = blockIdx.x * 64;
    float lw = lnw[lane], lb = lnb[lane];
    for (int rr = 0; rr < 16; ++rr) {
        int lr = wid * 16 + rr;
        float x = m[(size_t)(r0 + lr) * 64 + lane];
        float mu = waveReduceSum(x) * (1.0f / 64.0f);
        float d = x - mu;
        float var = waveReduceSum(d * d) * (1.0f / 64.0f);
        float xn = d * rsqrtf(var + 1e-5f) * lw + lb;
        int byt = lr * 128 + ((lane * 2) ^ ((lr & 7) << 4));
        *(unsigned short*)(As + byt) = f2bf(xn);
    }
    __syncthreads();
    int lr = wid * 16 + lc;
    int swz = (lr & 7) << 4;
    bf16x8 af0 = *(bf16x8*)(As + lr * 128 + ((g * 16) ^ swz));
    bf16x8 af1 = *(bf16x8*)(As + lr * 128 + ((64 + g * 16) ^ swz));
    f32x4 acc[16];
    #pragma unroll
    for (int fn = 0; fn < 16; ++fn) acc[fn] = (f32x4){0.f, 0.f, 0.f, 0.f};
    #pragma unroll
    for (int fn = 0; fn < 16; ++fn) {
        bf16x8 b0 = *(const bf16x8*)&Bt[(fn * 16 + lc) * 64 + g * 8];
        bf16x8 b1 = *(const bf16x8*)&Bt[(fn * 16 + lc) * 64 + 32 + g * 8];
        acc[fn] = __builtin_amdgcn_mfma_f32_16x16x32_bf16(af0, b0, acc[fn], 0, 0, 0);
        acc[fn] = __builtin_amdgcn_mfma_f32_16x16x32_bf16(af1, b1, acc[fn], 0, 0, 0);
    }
    if (mode == 0) {
        // scatter to vb[h][(s*32+d)][j]
        #pragma unroll
        for (int fn = 0; fn < 16; ++fn) {
            #pragma unroll
            for (int r = 0; r < 4; ++r) {
                int row = r0 + wid * 16 + g * 4 + r;
                int col = fn * 16 + lc;
                int h = col >> 5, d = col & 31;
                int s = row >> 8, j = row & 255;
                out[(size_t)((h << 14) + (s << 5) + d) * 256 + j] = __float2bfloat16(acc[fn][r]);
            }
        }
    } else {
        #pragma unroll
        for (int fn = 0; fn < 16; ++fn) {
            #pragma unroll
            for (int r = 0; r < 4; ++r) {
                int row = r0 + wid * 16 + g * 4 + r;
                int col = fn * 16 + lc;
                float sg = 1.0f / (1.0f + expf(-acc[fn][r]));
                out[(size_t)row * 256 + col] = __float2bfloat16(sg);
            }
        }
    }
}

// ---------------- K6a: per-h GEMM O[(s,d)][i] = vb . wlb^T -> obuf[(s,i)][hd] ----------------
__global__ __launch_bounds__(256) void k6a(
    const __hip_bfloat16* __restrict__ vb, const __hip_bfloat16* __restrict__ wlb,
    __hip_bfloat16* __restrict__ obuf) {
    __shared__ __align__(16) char smem[16384];
    char* As = smem;
    char* Bs = smem + 8192;
    int tid = threadIdx.x;
    int wid = tid >> 6, lane = tid & 63;
    int g = lane >> 4, lc = lane & 15;
    int idx = blockIdx.x;
    int h = idx >> 8, rem = idx & 255;
    int bm = rem >> 1, bn = rem & 1;
    int m0 = bm * 128, n0 = bn * 128;
    int wm = wid >> 1, wn = wid & 1;
    const __hip_bfloat16* vb_h = vb + (size_t)h * 16384 * 256;
    const __hip_bfloat16* wlb_h = wlb + (size_t)h * 256 * 256;

    f32x4 acc[4][4];
    #pragma unroll
    for (int fm = 0; fm < 4; ++fm)
        #pragma unroll
        for (int fn = 0; fn < 4; ++fn)
            acc[fm][fn] = (f32x4){0.f, 0.f, 0.f, 0.f};

    for (int k0 = 0; k0 < 256; k0 += 32) {
        __syncthreads();
        #pragma unroll
        for (int hh = 0; hh < 2; ++hh) {
            int c = hh * 256 + wid * 64 + lane;
            int r = c >> 2, gs = c & 3;
            int gk = gs ^ ((r >> 1) & 3);
            const __hip_bfloat16* ga = vb_h + (size_t)(m0 + r) * 256 + k0 + gk * 8;
            const __hip_bfloat16* gb = wlb_h + (size_t)(n0 + r) * 256 + k0 + gk * 8;
            gload_lds16(ga, As + hh * 4096 + wid * 1024);
            gload_lds16(gb, Bs + hh * 4096 + wid * 1024);
        }
        __syncthreads();
        bf16x8 af[4], bfr[4];
        #pragma unroll
        for (int fm = 0; fm < 4; ++fm) {
            int row = wm * 64 + fm * 16 + lc;
            int sw = (g * 16) ^ (((row >> 1) & 3) << 4);
            af[fm] = *(bf16x8*)(As + row * 64 + sw);
        }
        #pragma unroll
        for (int fn = 0; fn < 4; ++fn) {
            int row = wn * 64 + fn * 16 + lc;
            int sw = (g * 16) ^ (((row >> 1) & 3) << 4);
            bfr[fn] = *(bf16x8*)(Bs + row * 64 + sw);
        }
        #pragma unroll
        for (int fm = 0; fm < 4; ++fm)
            #pragma unroll
            for (int fn = 0; fn < 4; ++fn)
                acc[fm][fn] = __builtin_amdgcn_mfma_f32_16x16x32_bf16(
                    af[fm], bfr[fn], acc[fm][fn], 0, 0, 0);
    }
    #pragma unroll
    for (int fm = 0; fm < 4; ++fm) {
        #pragma unroll
        for (int fn = 0; fn < 4; ++fn) {
            #pragma unroll
            for (int r = 0; r < 4; ++r) {
                int mm = m0 + wm * 64 + fm * 16 + g * 4 + r;   // (s,d)
                int nn = n0 + wn * 64 + fn * 16 + lc;          // i
                int s = mm >> 5, d = mm & 31;
                obuf[(size_t)(s * 256 + nn) * 256 + h * 32 + d] = __float2bfloat16(acc[fm][fn][r]);
            }
        }
    }
}

// ---------------- K6b: mout = m + (gsig .* obuf) @ wo_t ----------------
// block = 128 rows, wave = 32 rows (2 m-frags), N=64 (4 n-frags), K=256
__global__ __launch_bounds__(256) void k6b(
    const __hip_bfloat16* __restrict__ obuf, const __hip_bfloat16* __restrict__ gsig,
    const __hip_bfloat16* __restrict__ wo_t, const float* __restrict__ m,
    float* __restrict__ mout) {
    int tid = threadIdx.x, wid = tid >> 6, lane = tid & 63;
    int g = lane >> 4, lc = lane & 15;
    int r0 = blockIdx.x * 128;
    f32x4 acc[2][4];
    #pragma unroll
    for (int fm = 0; fm < 2; ++fm)
        #pragma unroll
        for (int fn = 0; fn < 4; ++fn)
            acc[fm][fn] = (f32x4){0.f, 0.f, 0.f, 0.f};
    for (int ks = 0; ks < 8; ++ks) {
        bf16x8 af[2];
        #pragma unroll
        for (int fm = 0; fm < 2; ++fm) {
            int arow = r0 + wid * 32 + fm * 16 + lc;
            bf16x8 ao = *(const bf16x8*)&obuf[(size_t)arow * 256 + ks * 32 + g * 8];
            bf16x8 ag = *(const bf16x8*)&gsig[(size_t)arow * 256 + ks * 32 + g * 8];
            #pragma unroll
            for (int t = 0; t < 8; ++t)
                af[fm][t] = (short)f2bf(bfbits2f(ao[t]) * bfbits2f(ag[t]));
        }
        #pragma unroll
        for (int fn = 0; fn < 4; ++fn) {
            bf16x8 bf_ = *(const bf16x8*)&wo_t[(fn * 16 + lc) * 256 + ks * 32 + g * 8];
            acc[0][fn] = __builtin_amdgcn_mfma_f32_16x16x32_bf16(af[0], bf_, acc[0][fn], 0, 0, 0);
            acc[1][fn] = __builtin_amdgcn_mfma_f32_16x16x32_bf16(af[1], bf_, acc[1][fn], 0, 0, 0);
        }
    }
    #pragma unroll
    for (int fm = 0; fm < 2; ++fm)
        #pragma unroll
        for (int fn = 0; fn < 4; ++fn)
            #pragma unroll
            for (int r = 0; r < 4; ++r) {
                int row = r0 + wid * 32 + fm * 16 + g * 4 + r;
                int col = fn * 16 + lc;
                mout[(size_t)row * 64 + col] = m[(size_t)row * 64 + col] + acc[fm][fn][r];
            }
}

// ---------------- K7b: fused LN + SwiGLU GEMM -> hbuf bf16 [row][256] ----------------
// block = 64 rows, wave = 16 rows, N=512 (a|b), K=64
__global__ __launch_bounds__(256) void k7b(
    const float* __restrict__ mbuf, const float* __restrict__ lnw,
    const float* __restrict__ lnb, const __hip_bfloat16* __restrict__ wab_t,
    __hip_bfloat16* __restrict__ hbuf) {
    __shared__ __align__(16) char As[64 * 128];
    int tid = threadIdx.x, wid = tid >> 6, lane = tid & 63;
    int g = lane >> 4, lc = lane & 15;
    int r0 = blockIdx.x * 64;
    float lw = lnw[lane], lb = lnb[lane];
    for (int rr = 0; rr < 16; ++rr) {
        int lr = wid * 16 + rr;
        float x = mbuf[(size_t)(r0 + lr) * 64 + lane];
        float mu = waveReduceSum(x) * (1.0f / 64.0f);
        float d = x - mu;
        float var = waveReduceSum(d * d) * (1.0f / 64.0f);
        float xn = d * rsqrtf(var + 1e-5f) * lw + lb;
        int byt = lr * 128 + ((lane * 2) ^ ((lr & 7) << 4));
        *(unsigned short*)(As + byt) = f2bf(xn);
    }
    __syncthreads();
    int lr = wid * 16 + lc;
    int swz = (lr & 7) << 4;
    bf16x8 af0 = *(bf16x8*)(As + lr * 128 + ((g * 16) ^ swz));
    bf16x8 af1 = *(bf16x8*)(As + lr * 128 + ((64 + g * 16) ^ swz));
    f32x4 acc[32];
    #pragma unroll
    for (int fn = 0; fn < 32; ++fn) acc[fn] = (f32x4){0.f, 0.f, 0.f, 0.f};
    #pragma unroll
    for (int fn = 0; fn < 32; ++fn) {
        bf16x8 b0 = *(const bf16x8*)&wab_t[(fn * 16 + lc) * 64 + g * 8];
        bf16x8 b1 = *(const bf16x8*)&wab_t[(fn * 16 + lc) * 64 + 32 + g * 8];
        acc[fn] = __builtin_amdgcn_mfma_f32_16x16x32_bf16(af0, b0, acc[fn], 0, 0, 0);
        acc[fn] = __builtin_amdgcn_mfma_f32_16x16x32_bf16(af1, b1, acc[fn], 0, 0, 0);
    }
    #pragma unroll
    for (int fn = 0; fn < 16; ++fn) {
        #pragma unroll
        for (int r = 0; r < 4; ++r) {
            int row = r0 + wid * 16 + g * 4 + r;
            int f = fn * 16 + lc;
            float aa = acc[fn][r];
            float bb = acc[fn + 16][r];
            float sil = aa / (1.0f + expf(-aa));
            hbuf[(size_t)row * 256 + f] = __float2bfloat16(sil * bb);
        }
    }
}

// ---------------- K7c: mout += hbuf @ wo2_t ----------------
__global__ __launch_bounds__(256) void k7c(
    const __hip_bfloat16* __restrict__ hbuf, const __hip_bfloat16* __restrict__ wo2_t,
    float* __restrict__ mout) {
    int tid = threadIdx.x, wid = tid >> 6, lane = tid & 63;
    int g = lane >> 4, lc = lane & 15;
    int r0 = blockIdx.x * 128;
    f32x4 acc[2][4];
    #pragma unroll
    for (int fm = 0; fm < 2; ++fm)
        #pragma unroll
        for (int fn = 0; fn < 4; ++fn)
            acc[fm][fn] = (f32x4){0.f, 0.f, 0.f, 0.f};
    for (int ks = 0; ks < 8; ++ks) {
        bf16x8 af[2];
        #pragma unroll
        for (int fm = 0; fm < 2; ++fm) {
            int arow = r0 + wid * 32 + fm * 16 + lc;
            af[fm] = *(const bf16x8*)&hbuf[(size_t)arow * 256 + ks * 32 + g * 8];
        }
        #pragma unroll
        for (int fn = 0; fn < 4; ++fn) {
            bf16x8 bf_ = *(const bf16x8*)&wo2_t[(fn * 16 + lc) * 256 + ks * 32 + g * 8];
            acc[0][fn] = __builtin_amdgcn_mfma_f32_16x16x32_bf16(af[0], bf_, acc[0][fn], 0, 0, 0);
            acc[1][fn] = __builtin_amdgcn_mfma_f32_16x16x32_bf16(af[1], bf_, acc[1][fn], 0, 0, 0);
        }
    }
    #pragma unroll
    for (int fm = 0; fm < 2; ++fm)
        #pragma unroll
        for (int fn = 0; fn < 4; ++fn)
            #pragma unroll
            for (int r = 0; r < 4; ++r) {
                int row = r0 + wid * 32 + fm * 16 + g * 4 + r;
                int col = fn * 16 + lc;
                mout[(size_t)row * 64 + col] += acc[fm][fn][r];
            }
}

extern "C" void kernel_launch(void* const* d_in, const int* in_sizes, int n_in,
                              void* d_out, int out_size, void* d_ws, size_t ws_size,
                              hipStream_t stream) {
    const float* m        = (const float*)d_in[0];
    const float* z        = (const float*)d_in[1];
    const float* mask     = (const float*)d_in[2];
    const float* opm_ln_w = (const float*)d_in[3];
    const float* opm_ln_b = (const float*)d_in[4];
    const float* opm_w1   = (const float*)d_in[5];
    const float* opm_w2   = (const float*)d_in[6];
    const float* opm_wout = (const float*)d_in[7];
    const float* opm_bout = (const float*)d_in[8];
    const float* pwa_lnm_w = (const float*)d_in[9];
    const float* pwa_lnm_b = (const float*)d_in[10];
    const float* pwa_lnz_w = (const float*)d_in[11];
    const float* pwa_lnz_b = (const float*)d_in[12];
    const float* pwa_wv   = (const float*)d_in[13];
    const float* pwa_wz   = (const float*)d_in[14];
    const float* pwa_wg   = (const float*)d_in[15];
    const float* pwa_wo   = (const float*)d_in[16];
    const float* tr_ln_w  = (const float*)d_in[17];
    const float* tr_ln_b  = (const float*)d_in[18];
    const float* tr_wa    = (const float*)d_in[19];
    const float* tr_wb    = (const float*)d_in[20];
    const float* tr_wo    = (const float*)d_in[21];

    float* m_out = (float*)d_out;                  // (S*N, 64)
    float* z_out = m_out + (size_t)S * N * CM;     // (N*N, 128)

    // ---- workspace layout (~131.7 MiB) ----
    char* w = (char*)d_ws;
    __hip_bfloat16* wout_t = (__hip_bfloat16*)w;                 // 262144 B
    __hip_bfloat16* wv_t   = (__hip_bfloat16*)(w + 262144);      // 32768
    __hip_bfloat16* wg_t   = (__hip_bfloat16*)(w + 294912);      // 32768
    __hip_bfloat16* wab_t  = (__hip_bfloat16*)(w + 327680);      // 65536
    __hip_bfloat16* wo_t   = (__hip_bfloat16*)(w + 393216);      // 32768
    __hip_bfloat16* wo2_t  = (__hip_bfloat16*)(w + 425984);      // 32768
    float* normb           = (float*)(w + 458752);               // 262144
    float* wl              = (float*)(w + 720896);               // 2097152
    __hip_bfloat16* wlb    = (__hip_bfloat16*)(w + 2818048);     // 1048576
    char* bufA             = w + 3866624;                        // 67108864: a_t|b_t -> vb -> gsig
    char* bufB             = w + 70975488;                       // 67108864: obuf -> hbuf

    __hip_bfloat16* a_t  = (__hip_bfloat16*)bufA;
    __hip_bfloat16* b_t  = a_t + 4194304;
    __hip_bfloat16* vb   = (__hip_bfloat16*)bufA;   // after k2
    __hip_bfloat16* gsig = (__hip_bfloat16*)bufA;   // after k6a (overwrites vb)
    __hip_bfloat16* obuf = (__hip_bfloat16*)bufB;
    __hip_bfloat16* hbuf = (__hip_bfloat16*)bufB;   // after k6b

    k0_prep<<<896, 256, 0, stream>>>(opm_wout, pwa_wv, pwa_wg, tr_wa, tr_wb, pwa_wo, tr_wo,
                                     wout_t, wv_t, wg_t, wab_t, wo_t, wo2_t);
    k1_ab<<<2048, 256, 0, stream>>>(m, mask, opm_ln_w, opm_ln_b, opm_w1, opm_w2, a_t, b_t);
    k1b_norm<<<N, 256, 0, stream>>>(mask, normb);
    k2_opm<<<4096, 256, 0, stream>>>(a_t, b_t, wout_t, opm_bout, normb, z, z_out);
    k3_logits<<<N * N / 4, 256, 0, stream>>>(z_out, pwa_lnz_w, pwa_lnz_b, pwa_wz, wl);
    k4_softmax<<<N * H, 256, 0, stream>>>(wl, wlb);
    k5vg<<<2048, 256, 0, stream>>>(m, pwa_lnm_w, pwa_lnm_b, wv_t, vb, 0);
    k6a<<<2048, 256, 0, stream>>>(vb, wlb, obuf);
    k5vg<<<2048, 256, 0, stream>>>(m, pwa_lnm_w, pwa_lnm_b, wg_t, gsig, 1);
    k6b<<<1024, 256, 0, stream>>>(obuf, gsig, wo_t, m, m_out);
    k7b<<<2048, 256, 0, stream>>>(m_out, tr_ln_w, tr_ln_b, wab_t, hbuf);
    k7c<<<1024, 256, 0, stream>>>(hbuf, wo2_t, m_out);
}

// Round 4
// 804.738 us; speedup vs baseline: 3.9531x; 1.0277x over previous
//
#include <hip/hip_runtime.h>
#include <hip/hip_bf16.h>

// dims (compile-time)
#define S 512
#define N 256
#define CM 64
#define CZ 128
#define CH 32
#define H 8
#define DH 32
#define FF 256
#define HDH 256   // H*DH

typedef __attribute__((ext_vector_type(8))) short bf16x8;
typedef __attribute__((ext_vector_type(4))) float f32x4;

__device__ __forceinline__ float waveReduceSum(float v) {
    #pragma unroll
    for (int off = 32; off > 0; off >>= 1) v += __shfl_xor(v, off);
    return v;
}
__device__ __forceinline__ float waveReduceMax(float v) {
    #pragma unroll
    for (int off = 32; off > 0; off >>= 1) v = fmaxf(v, __shfl_xor(v, off));
    return v;
}
__device__ __forceinline__ unsigned short f2bf(float x) {
    __hip_bfloat16 h = __float2bfloat16(x);
    return *reinterpret_cast<unsigned short*>(&h);
}
__device__ __forceinline__ float bfbits2f(short u) {
    unsigned int x = ((unsigned int)(unsigned short)u) << 16;
    return __uint_as_float(x);
}
__device__ __forceinline__ void gload_lds16(const void* g, void* l) {
    __builtin_amdgcn_global_load_lds(
        (const __attribute__((address_space(1))) unsigned int*)g,
        (__attribute__((address_space(3))) unsigned int*)l, 16, 0, 0);
}

// ---------------- K0: weight transposes to bf16 ----------------
__global__ __launch_bounds__(256) void k0_prep(
    const float* __restrict__ wout, const float* __restrict__ wv,
    const float* __restrict__ wg, const float* __restrict__ wa,
    const float* __restrict__ wb, const float* __restrict__ wo,
    const float* __restrict__ wo2,
    __hip_bfloat16* __restrict__ wout_t, __hip_bfloat16* __restrict__ wv_t,
    __hip_bfloat16* __restrict__ wg_t, __hip_bfloat16* __restrict__ wab_t,
    __hip_bfloat16* __restrict__ wo_t, __hip_bfloat16* __restrict__ wo2_t) {
    int idx = blockIdx.x * 256 + threadIdx.x;
    if (idx < 131072) {
        int f = idx >> 10, k = idx & 1023;
        wout_t[idx] = __float2bfloat16(wout[k * 128 + f]);
    } else if (idx < 147456) {
        int t = idx - 131072; int n = t >> 6, k = t & 63;
        wv_t[t] = __float2bfloat16(wv[k * 256 + n]);
    } else if (idx < 163840) {
        int t = idx - 147456; int n = t >> 6, k = t & 63;
        wg_t[t] = __float2bfloat16(wg[k * 256 + n]);
    } else if (idx < 196608) {
        int t = idx - 163840; int n = t >> 6, k = t & 63;
        wab_t[t] = __float2bfloat16(n < 256 ? wa[k * 256 + n] : wb[k * 256 + (n - 256)]);
    } else if (idx < 212992) {
        int t = idx - 196608; int n = t >> 8, k = t & 255;
        wo_t[t] = __float2bfloat16(wo[k * 64 + n]);
    } else if (idx < 229376) {
        int t = idx - 212992; int n = t >> 8, k = t & 255;
        wo2_t[t] = __float2bfloat16(wo2[k * 64 + n]);
    }
}

// ---------------- K1: OPM layernorm + a/b projections, transposed bf16 out ----------------
__global__ __launch_bounds__(256) void k1_ab(
    const float* __restrict__ m, const float* __restrict__ mask,
    const float* __restrict__ lnw, const float* __restrict__ lnb,
    const float* __restrict__ w1, const float* __restrict__ w2,
    __hip_bfloat16* __restrict__ a_t, __hip_bfloat16* __restrict__ b_t) {
    __shared__ float mn[64][64];
    __shared__ float mk[64];
    int tid = threadIdx.x, w = tid >> 6, lane = tid & 63;
    int i = blockIdx.x >> 3, s0 = (blockIdx.x & 7) * 64;
    float lw = lnw[lane], lb = lnb[lane];
    for (int rr = 0; rr < 16; ++rr) {
        int sl = w * 16 + rr;
        float x = m[((size_t)(s0 + sl) * 256 + i) * 64 + lane];
        float mu = waveReduceSum(x) * (1.0f / 64.0f);
        float d = x - mu;
        float var = waveReduceSum(d * d) * (1.0f / 64.0f);
        mn[sl][lane] = d * rsqrtf(var + 1e-5f) * lw + lb;
        if (lane == 0) mk[sl] = mask[(s0 + sl) * 256 + i];
    }
    __syncthreads();
    int e = lane & 31;
    const float* W = (lane < 32) ? w1 : w2;
    __hip_bfloat16* dst = (lane < 32) ? a_t : b_t;
    float acc[16];
    #pragma unroll
    for (int ss = 0; ss < 16; ++ss) acc[ss] = 0.f;
    for (int c = 0; c < 64; ++c) {
        float wc = W[c * 32 + e];
        #pragma unroll
        for (int ss = 0; ss < 16; ++ss)
            acc[ss] += mn[w * 16 + ss][c] * wc;
    }
    __hip_bfloat16 outv[16];
    #pragma unroll
    for (int ss = 0; ss < 16; ++ss)
        outv[ss] = __float2bfloat16(acc[ss] * mk[w * 16 + ss]);
    __hip_bfloat16* p = dst + (size_t)(i * 32 + e) * 512 + s0 + w * 16;
    *(bf16x8*)p = *(bf16x8*)&outv[0];
    *(bf16x8*)(p + 8) = *(bf16x8*)&outv[8];
}

// ---------------- K1b: norm[i,j] = sum_s mask[s,i]*mask[s,j] ----------------
__global__ __launch_bounds__(256) void k1b_norm(
    const float* __restrict__ mask, float* __restrict__ normb) {
    __shared__ float mcol[512];
    int i = blockIdx.x, t = threadIdx.x;
    mcol[t] = mask[t * 256 + i];
    mcol[t + 256] = mask[(t + 256) * 256 + i];
    __syncthreads();
    float acc = 0.f;
    for (int s = 0; s < 512; ++s) acc += mcol[s] * mask[s * 256 + t];
    normb[i * 256 + t] = acc;
}

// ---------------- K2: OPM bf16 MFMA GEMM (prefetch dbuf) + fused wout projection ----------------
__global__ __launch_bounds__(256) void k2_opm(
    const __hip_bfloat16* __restrict__ a_t, const __hip_bfloat16* __restrict__ b_t,
    const __hip_bfloat16* __restrict__ wout_t, const float* __restrict__ bout,
    const float* __restrict__ normb, const float* __restrict__ zin,
    float* __restrict__ zout) {
    __shared__ __align__(16) char smem[32768];
    int tid = threadIdx.x;
    int wid = tid >> 6, lane = tid & 63;
    int g = lane >> 4, lc = lane & 15;
    int bm = blockIdx.x >> 6, bn = blockIdx.x & 63;
    int m0 = bm * 128, n0 = bn * 128;
    int wm = wid >> 1, wn = wid & 1;

    // staging source address pieces (lane-dependent, k0-independent)
    int c_ = wid * 64 + lane;            // first half id base (h adds 256)
    f32x4 acc[4][4];
    #pragma unroll
    for (int fm = 0; fm < 4; ++fm)
        #pragma unroll
        for (int fn = 0; fn < 4; ++fn)
            acc[fm][fn] = (f32x4){0.f, 0.f, 0.f, 0.f};

    auto stage = [&](int sel, int k0) {
        #pragma unroll
        for (int h = 0; h < 2; ++h) {
            int c = h * 256 + c_;
            int r = c >> 2, gs = c & 3;
            int gk = gs ^ ((r >> 1) & 3);
            const __hip_bfloat16* ga = a_t + (size_t)(m0 + r) * 512 + k0 + gk * 8;
            const __hip_bfloat16* gb = b_t + (size_t)(n0 + r) * 512 + k0 + gk * 8;
            gload_lds16(ga, smem + sel * 16384 + h * 4096 + wid * 1024);
            gload_lds16(gb, smem + sel * 16384 + 8192 + h * 4096 + wid * 1024);
        }
    };

    stage(0, 0);
    __syncthreads();           // drains vmcnt(0): buf0 ready
    int cur = 0;
    for (int t = 0; t < 16; ++t) {
        if (t < 15) stage(cur ^ 1, (t + 1) * 32);   // prefetch next tile (in flight during compute)
        char* As = smem + cur * 16384;
        char* Bs = As + 8192;
        bf16x8 af[4], bfr[4];
        #pragma unroll
        for (int fm = 0; fm < 4; ++fm) {
            int row = wm * 64 + fm * 16 + lc;
            int sw = (g * 16) ^ (((row >> 1) & 3) << 4);
            af[fm] = *(bf16x8*)(As + row * 64 + sw);
        }
        #pragma unroll
        for (int fn = 0; fn < 4; ++fn) {
            int row = wn * 64 + fn * 16 + lc;
            int sw = (g * 16) ^ (((row >> 1) & 3) << 4);
            bfr[fn] = *(bf16x8*)(Bs + row * 64 + sw);
        }
        #pragma unroll
        for (int fm = 0; fm < 4; ++fm)
            #pragma unroll
            for (int fn = 0; fn < 4; ++fn)
                acc[fm][fn] = __builtin_amdgcn_mfma_f32_16x16x32_bf16(
                    af[fm], bfr[fn], acc[fm][fn], 0, 0, 0);
        __syncthreads();       // implicit vmcnt(0): prefetched tile ready; buf reuse safe
        cur ^= 1;
    }
    // ---- dump accumulators to Cp[pair][1024] bf16 (swizzled) ----
    #pragma unroll
    for (int fm = 0; fm < 4; ++fm) {
        int i_loc = wm * 2 + (fm >> 1);
        #pragma unroll
        for (int fn = 0; fn < 4; ++fn) {
            int j_loc = wn * 2 + (fn >> 1);
            int pair = i_loc * 4 + j_loc;
            int xorp = (pair & 7) << 4;
            #pragma unroll
            for (int r = 0; r < 4; ++r) {
                int mm31 = (fm & 1) * 16 + g * 4 + r;
                int nn31 = (fn & 1) * 16 + lc;
                int off = mm31 * 64 + nn31 * 2;
                int offs = off ^ xorp ^ (((off >> 8) & 3) << 4);
                *(unsigned short*)(smem + pair * 2048 + offs) = f2bf(acc[fm][fn][r]);
            }
        }
    }
    __syncthreads();
    f32x4 acc2[2];
    acc2[0] = (f32x4){0.f, 0.f, 0.f, 0.f};
    acc2[1] = (f32x4){0.f, 0.f, 0.f, 0.f};
    int f0 = wid * 32;
    int pr = lc;
    int xorp2 = (pr & 7) << 4;
    for (int k2 = 0; k2 < 1024; k2 += 32) {
        int offA = k2 * 2 + g * 16;
        int offAs = offA ^ xorp2 ^ (((offA >> 8) & 3) << 4);
        bf16x8 af2 = *(bf16x8*)(smem + pr * 2048 + offAs);
        #pragma unroll
        for (int fn2 = 0; fn2 < 2; ++fn2) {
            int f = f0 + fn2 * 16 + lc;
            bf16x8 bw = *(const bf16x8*)(wout_t + (size_t)f * 1024 + k2 + g * 8);
            acc2[fn2] = __builtin_amdgcn_mfma_f32_16x16x32_bf16(af2, bw, acc2[fn2], 0, 0, 0);
        }
    }
    #pragma unroll
    for (int fn2 = 0; fn2 < 2; ++fn2) {
        #pragma unroll
        for (int r = 0; r < 4; ++r) {
            int pair = g * 4 + r;
            int i = bm * 4 + (pair >> 2), j = bn * 4 + (pair & 3);
            int ij = i * 256 + j;
            int f = f0 + fn2 * 16 + lc;
            float d = acc2[fn2][r];
            zout[(size_t)ij * 128 + f] = zin[(size_t)ij * 128 + f] +
                (d + bout[f]) / (normb[ij] + 1e-3f);
        }
    }
}

// ---------------- K3: logits[i,h,j] = LN(z_new[i,j,:]) @ wz ----------------
__global__ __launch_bounds__(256) void k3_logits(
    const float* __restrict__ zout, const float* __restrict__ lnzw,
    const float* __restrict__ lnzb, const float* __restrict__ wz,
    float* __restrict__ wl) {
    __shared__ float znL[4][128];
    int tid = threadIdx.x, w = tid >> 6, lane = tid & 63;
    int pair = blockIdx.x * 4 + w;
    float z0 = zout[pair * 128 + lane];
    float z1 = zout[pair * 128 + 64 + lane];
    float mu = waveReduceSum(z0 + z1) * (1.0f / 128.0f);
    float d0 = z0 - mu, d1 = z1 - mu;
    float var = waveReduceSum(d0 * d0 + d1 * d1) * (1.0f / 128.0f);
    float rstd = rsqrtf(var + 1e-5f);
    znL[w][lane] = d0 * rstd * lnzw[lane] + lnzb[lane];
    znL[w][lane + 64] = d1 * rstd * lnzw[lane + 64] + lnzb[lane + 64];
    __syncthreads();
    int h = lane >> 3, chunk = lane & 7;
    float p = 0.f;
    #pragma unroll
    for (int cc = 0; cc < 16; ++cc) {
        int c = chunk * 16 + cc;
        p += znL[w][c] * wz[c * 8 + h];
    }
    p += __shfl_xor(p, 1); p += __shfl_xor(p, 2); p += __shfl_xor(p, 4);
    if (chunk == 0) {
        int i = pair >> 8, j = pair & 255;
        wl[(i * 8 + h) * 256 + j] = p;
    }
}

// ---------------- K4: softmax over j; write bf16 wlb[h][i][j] ----------------
__global__ __launch_bounds__(256) void k4_softmax(
    const float* __restrict__ wl, __hip_bfloat16* __restrict__ wlb) {
    __shared__ float red[8];
    int row = blockIdx.x, t = threadIdx.x;   // row = i*8+h
    int w = t >> 6, lane = t & 63;
    float v = wl[row * 256 + t];
    float mx = waveReduceMax(v);
    if (lane == 0) red[w] = mx;
    __syncthreads();
    mx = fmaxf(fmaxf(red[0], red[1]), fmaxf(red[2], red[3]));
    float ex = expf(v - mx);
    float sm = waveReduceSum(ex);
    if (lane == 0) red[4 + w] = sm;
    __syncthreads();
    float tot = red[4] + red[5] + red[6] + red[7];
    int i = row >> 3, h = row & 7;
    wlb[((h << 8) | i) * 256 + t] = __float2bfloat16(ex / tot);
}

// ---------------- K5: fused LN + [64->256] GEMM, v scatter ----------------
__global__ __launch_bounds__(256) void k5v(
    const float* __restrict__ m, const float* __restrict__ lnw,
    const float* __restrict__ lnb, const __hip_bfloat16* __restrict__ Bt,
    __hip_bfloat16* __restrict__ out) {
    __shared__ __align__(16) char As[64 * 128];
    int tid = threadIdx.x, wid = tid >> 6, lane = tid & 63;
    int g = lane >> 4, lc = lane & 15;
    int r0 = blockIdx.x * 64;
    float lw = lnw[lane], lb = lnb[lane];
    for (int rr = 0; rr < 16; ++rr) {
        int lr = wid * 16 + rr;
        float x = m[(size_t)(r0 + lr) * 64 + lane];
        float mu = waveReduceSum(x) * (1.0f / 64.0f);
        float d = x - mu;
        float var = waveReduceSum(d * d) * (1.0f / 64.0f);
        float xn = d * rsqrtf(var + 1e-5f) * lw + lb;
        int byt = lr * 128 + ((lane * 2) ^ ((lr & 7) << 4));
        *(unsigned short*)(As + byt) = f2bf(xn);
    }
    __syncthreads();
    int lr = wid * 16 + lc;
    int swz = (lr & 7) << 4;
    bf16x8 af0 = *(bf16x8*)(As + lr * 128 + ((g * 16) ^ swz));
    bf16x8 af1 = *(bf16x8*)(As + lr * 128 + ((64 + g * 16) ^ swz));
    f32x4 acc[16];
    #pragma unroll
    for (int fn = 0; fn < 16; ++fn) acc[fn] = (f32x4){0.f, 0.f, 0.f, 0.f};
    #pragma unroll
    for (int fn = 0; fn < 16; ++fn) {
        bf16x8 b0 = *(const bf16x8*)&Bt[(fn * 16 + lc) * 64 + g * 8];
        bf16x8 b1 = *(const bf16x8*)&Bt[(fn * 16 + lc) * 64 + 32 + g * 8];
        acc[fn] = __builtin_amdgcn_mfma_f32_16x16x32_bf16(af0, b0, acc[fn], 0, 0, 0);
        acc[fn] = __builtin_amdgcn_mfma_f32_16x16x32_bf16(af1, b1, acc[fn], 0, 0, 0);
    }
    // scatter to vb[h][(s*32+d)][j]
    #pragma unroll
    for (int fn = 0; fn < 16; ++fn) {
        #pragma unroll
        for (int r = 0; r < 4; ++r) {
            int row = r0 + wid * 16 + g * 4 + r;
            int col = fn * 16 + lc;
            int h = col >> 5, d = col & 31;
            int s = row >> 8, j = row & 255;
            out[(size_t)((h << 14) + (s << 5) + d) * 256 + j] = __float2bfloat16(acc[fn][r]);
        }
    }
}

// ---------------- K6a: per-h GEMM O[(s,d)][i] = vb . wlb^T -> obuf[(s,i)][hd] ----------------
__global__ __launch_bounds__(256) void k6a(
    const __hip_bfloat16* __restrict__ vb, const __hip_bfloat16* __restrict__ wlb,
    __hip_bfloat16* __restrict__ obuf) {
    __shared__ __align__(16) char smem[32768];
    int tid = threadIdx.x;
    int wid = tid >> 6, lane = tid & 63;
    int g = lane >> 4, lc = lane & 15;
    int idx = blockIdx.x;
    int h = idx >> 8, rem = idx & 255;
    int bm = rem >> 1, bn = rem & 1;
    int m0 = bm * 128, n0 = bn * 128;
    int wm = wid >> 1, wn = wid & 1;
    const __hip_bfloat16* vb_h = vb + (size_t)h * 16384 * 256;
    const __hip_bfloat16* wlb_h = wlb + (size_t)h * 256 * 256;
    int c_ = wid * 64 + lane;

    f32x4 acc[4][4];
    #pragma unroll
    for (int fm = 0; fm < 4; ++fm)
        #pragma unroll
        for (int fn = 0; fn < 4; ++fn)
            acc[fm][fn] = (f32x4){0.f, 0.f, 0.f, 0.f};

    auto stage = [&](int sel, int k0) {
        #pragma unroll
        for (int hh = 0; hh < 2; ++hh) {
            int c = hh * 256 + c_;
            int r = c >> 2, gs = c & 3;
            int gk = gs ^ ((r >> 1) & 3);
            const __hip_bfloat16* ga = vb_h + (size_t)(m0 + r) * 256 + k0 + gk * 8;
            const __hip_bfloat16* gb = wlb_h + (size_t)(n0 + r) * 256 + k0 + gk * 8;
            gload_lds16(ga, smem + sel * 16384 + hh * 4096 + wid * 1024);
            gload_lds16(gb, smem + sel * 16384 + 8192 + hh * 4096 + wid * 1024);
        }
    };

    stage(0, 0);
    __syncthreads();
    int cur = 0;
    for (int t = 0; t < 8; ++t) {
        if (t < 7) stage(cur ^ 1, (t + 1) * 32);
        char* As = smem + cur * 16384;
        char* Bs = As + 8192;
        bf16x8 af[4], bfr[4];
        #pragma unroll
        for (int fm = 0; fm < 4; ++fm) {
            int row = wm * 64 + fm * 16 + lc;
            int sw = (g * 16) ^ (((row >> 1) & 3) << 4);
            af[fm] = *(bf16x8*)(As + row * 64 + sw);
        }
        #pragma unroll
        for (int fn = 0; fn < 4; ++fn) {
            int row = wn * 64 + fn * 16 + lc;
            int sw = (g * 16) ^ (((row >> 1) & 3) << 4);
            bfr[fn] = *(bf16x8*)(Bs + row * 64 + sw);
        }
        #pragma unroll
        for (int fm = 0; fm < 4; ++fm)
            #pragma unroll
            for (int fn = 0; fn < 4; ++fn)
                acc[fm][fn] = __builtin_amdgcn_mfma_f32_16x16x32_bf16(
                    af[fm], bfr[fn], acc[fm][fn], 0, 0, 0);
        __syncthreads();
        cur ^= 1;
    }
    #pragma unroll
    for (int fm = 0; fm < 4; ++fm) {
        #pragma unroll
        for (int fn = 0; fn < 4; ++fn) {
            #pragma unroll
            for (int r = 0; r < 4; ++r) {
                int mm = m0 + wm * 64 + fm * 16 + g * 4 + r;   // (s,d)
                int nn = n0 + wn * 64 + fn * 16 + lc;          // i
                int s = mm >> 5, d = mm & 31;
                obuf[(size_t)(s * 256 + nn) * 256 + h * 32 + d] = __float2bfloat16(acc[fm][fn][r]);
            }
        }
    }
}

// ---------------- K67: fused gate + PWA out-proj + Transition (SwiGLU) ----------------
// 64 rows/block. Phases: LN(m) -> g=sig(xn@wg) -> mnew = m+(obuf.*g)@wo -> LN ->
// h=swiglu(xn2@wab) -> out = mnew + h@wo2.
__global__ __launch_bounds__(256) void k67(
    const float* __restrict__ m,
    const float* __restrict__ lnmw, const float* __restrict__ lnmb,
    const __hip_bfloat16* __restrict__ wg_t, const __hip_bfloat16* __restrict__ wo_t,
    const __hip_bfloat16* __restrict__ obuf,
    const float* __restrict__ trlnw, const float* __restrict__ trlnb,
    const __hip_bfloat16* __restrict__ wab_t, const __hip_bfloat16* __restrict__ wo2_t,
    float* __restrict__ mout) {
    __shared__ __align__(16) char xnS[8192];        // [64 rows][128B] bf16, swizzled
    __shared__ __align__(16) char ghS[32768];       // [64 rows][512B] bf16, swizzled (g then h)
    __shared__ float mnS[64][68];                   // mnew f32
    int tid = threadIdx.x, wid = tid >> 6, lane = tid & 63;
    int g = lane >> 4, lc = lane & 15;
    int r0 = blockIdx.x * 64;
    int lr = wid * 16 + lc;
    int swz = (lr & 7) << 4;

    // ---- A: LN(m) -> xnS ----
    {
        float lw = lnmw[lane], lb = lnmb[lane];
        for (int rr = 0; rr < 16; ++rr) {
            int r2 = wid * 16 + rr;
            float x = m[(size_t)(r0 + r2) * 64 + lane];
            float mu = waveReduceSum(x) * (1.0f / 64.0f);
            float d = x - mu;
            float var = waveReduceSum(d * d) * (1.0f / 64.0f);
            float xn = d * rsqrtf(var + 1e-5f) * lw + lb;
            *(unsigned short*)(xnS + r2 * 128 + ((lane * 2) ^ ((r2 & 7) << 4))) = f2bf(xn);
        }
    }
    __syncthreads();
    // ---- B: g = sigmoid(xn @ wg_t) -> ghS ----
    {
        bf16x8 af0 = *(bf16x8*)(xnS + lr * 128 + ((g * 16) ^ swz));
        bf16x8 af1 = *(bf16x8*)(xnS + lr * 128 + ((64 + g * 16) ^ swz));
        #pragma unroll
        for (int fn = 0; fn < 16; ++fn) {
            f32x4 a_ = (f32x4){0.f, 0.f, 0.f, 0.f};
            bf16x8 b0 = *(const bf16x8*)&wg_t[(fn * 16 + lc) * 64 + g * 8];
            bf16x8 b1 = *(const bf16x8*)&wg_t[(fn * 16 + lc) * 64 + 32 + g * 8];
            a_ = __builtin_amdgcn_mfma_f32_16x16x32_bf16(af0, b0, a_, 0, 0, 0);
            a_ = __builtin_amdgcn_mfma_f32_16x16x32_bf16(af1, b1, a_, 0, 0, 0);
            #pragma unroll
            for (int r = 0; r < 4; ++r) {
                int row = wid * 16 + g * 4 + r, col = fn * 16 + lc;
                float sg = 1.0f / (1.0f + expf(-a_[r]));
                *(unsigned short*)(ghS + row * 512 + ((col * 2) ^ ((row & 7) << 4))) = f2bf(sg);
            }
        }
    }
    __syncthreads();
    // ---- C: mnew = m + (obuf .* g) @ wo_t -> mnS ----
    {
        f32x4 acc[4];
        #pragma unroll
        for (int fn = 0; fn < 4; ++fn) acc[fn] = (f32x4){0.f, 0.f, 0.f, 0.f};
        for (int ks = 0; ks < 8; ++ks) {
            bf16x8 ao = *(const bf16x8*)&obuf[(size_t)(r0 + lr) * 256 + ks * 32 + g * 8];
            bf16x8 ag = *(bf16x8*)(ghS + lr * 512 + ((ks * 64 + g * 16) ^ swz));
            bf16x8 af;
            #pragma unroll
            for (int t = 0; t < 8; ++t)
                af[t] = (short)f2bf(bfbits2f(ao[t]) * bfbits2f(ag[t]));
            #pragma unroll
            for (int fn = 0; fn < 4; ++fn) {
                bf16x8 bf_ = *(const bf16x8*)&wo_t[(fn * 16 + lc) * 256 + ks * 32 + g * 8];
                acc[fn] = __builtin_amdgcn_mfma_f32_16x16x32_bf16(af, bf_, acc[fn], 0, 0, 0);
            }
        }
        #pragma unroll
        for (int fn = 0; fn < 4; ++fn)
            #pragma unroll
            for (int r = 0; r < 4; ++r) {
                int row = wid * 16 + g * 4 + r, col = fn * 16 + lc;
                mnS[row][col] = m[(size_t)(r0 + row) * 64 + col] + acc[fn][r];
            }
    }
    __syncthreads();
    // ---- D: LN(mnew) -> xnS ----
    {
        float lw = trlnw[lane], lb = trlnb[lane];
        for (int rr = 0; rr < 16; ++rr) {
            int r2 = wid * 16 + rr;
            float x = mnS[r2][lane];
            float mu = waveReduceSum(x) * (1.0f / 64.0f);
            float d = x - mu;
            float var = waveReduceSum(d * d) * (1.0f / 64.0f);
            float xn = d * rsqrtf(var + 1e-5f) * lw + lb;
            *(unsigned short*)(xnS + r2 * 128 + ((lane * 2) ^ ((r2 & 7) << 4))) = f2bf(xn);
        }
    }
    __syncthreads();
    // ---- E: h = silu(xn@wa)*(xn@wb) -> ghS ----
    {
        bf16x8 af0 = *(bf16x8*)(xnS + lr * 128 + ((g * 16) ^ swz));
        bf16x8 af1 = *(bf16x8*)(xnS + lr * 128 + ((64 + g * 16) ^ swz));
        f32x4 acc[32];
        #pragma unroll
        for (int fn = 0; fn < 32; ++fn) acc[fn] = (f32x4){0.f, 0.f, 0.f, 0.f};
        #pragma unroll
        for (int fn = 0; fn < 32; ++fn) {
            bf16x8 b0 = *(const bf16x8*)&wab_t[(fn * 16 + lc) * 64 + g * 8];
            bf16x8 b1 = *(const bf16x8*)&wab_t[(fn * 16 + lc) * 64 + 32 + g * 8];
            acc[fn] = __builtin_amdgcn_mfma_f32_16x16x32_bf16(af0, b0, acc[fn], 0, 0, 0);
            acc[fn] = __builtin_amdgcn_mfma_f32_16x16x32_bf16(af1, b1, acc[fn], 0, 0, 0);
        }
        #pragma unroll
        for (int fn = 0; fn < 16; ++fn) {
            #pragma unroll
            for (int r = 0; r < 4; ++r) {
                int row = wid * 16 + g * 4 + r, f = fn * 16 + lc;
                float aa = acc[fn][r];
                float bb = acc[fn + 16][r];
                float sil = aa / (1.0f + expf(-aa));
                *(unsigned short*)(ghS + row * 512 + ((f * 2) ^ ((row & 7) << 4))) = f2bf(sil * bb);
            }
        }
    }
    __syncthreads();
    // ---- F: out = mnew + h @ wo2_t ----
    {
        f32x4 acc[4];
        #pragma unroll
        for (int fn = 0; fn < 4; ++fn) acc[fn] = (f32x4){0.f, 0.f, 0.f, 0.f};
        for (int ks = 0; ks < 8; ++ks) {
            bf16x8 af = *(bf16x8*)(ghS + lr * 512 + ((ks * 64 + g * 16) ^ swz));
            #pragma unroll
            for (int fn = 0; fn < 4; ++fn) {
                bf16x8 bf_ = *(const bf16x8*)&wo2_t[(fn * 16 + lc) * 256 + ks * 32 + g * 8];
                acc[fn] = __builtin_amdgcn_mfma_f32_16x16x32_bf16(af, bf_, acc[fn], 0, 0, 0);
            }
        }
        #pragma unroll
        for (int fn = 0; fn < 4; ++fn)
            #pragma unroll
            for (int r = 0; r < 4; ++r) {
                int row = wid * 16 + g * 4 + r, col = fn * 16 + lc;
                mout[(size_t)(r0 + row) * 64 + col] = mnS[row][col] + acc[fn][r];
            }
    }
}

extern "C" void kernel_launch(void* const* d_in, const int* in_sizes, int n_in,
                              void* d_out, int out_size, void* d_ws, size_t ws_size,
                              hipStream_t stream) {
    const float* m        = (const float*)d_in[0];
    const float* z        = (const float*)d_in[1];
    const float* mask     = (const float*)d_in[2];
    const float* opm_ln_w = (const float*)d_in[3];
    const float* opm_ln_b = (const float*)d_in[4];
    const float* opm_w1   = (const float*)d_in[5];
    const float* opm_w2   = (const float*)d_in[6];
    const float* opm_wout = (const float*)d_in[7];
    const float* opm_bout = (const float*)d_in[8];
    const float* pwa_lnm_w = (const float*)d_in[9];
    const float* pwa_lnm_b = (const float*)d_in[10];
    const float* pwa_lnz_w = (const float*)d_in[11];
    const float* pwa_lnz_b = (const float*)d_in[12];
    const float* pwa_wv   = (const float*)d_in[13];
    const float* pwa_wz   = (const float*)d_in[14];
    const float* pwa_wg   = (const float*)d_in[15];
    const float* pwa_wo   = (const float*)d_in[16];
    const float* tr_ln_w  = (const float*)d_in[17];
    const float* tr_ln_b  = (const float*)d_in[18];
    const float* tr_wa    = (const float*)d_in[19];
    const float* tr_wb    = (const float*)d_in[20];
    const float* tr_wo    = (const float*)d_in[21];

    float* m_out = (float*)d_out;                  // (S*N, 64)
    float* z_out = m_out + (size_t)S * N * CM;     // (N*N, 128)

    // ---- workspace layout (~131.7 MiB) ----
    char* w = (char*)d_ws;
    __hip_bfloat16* wout_t = (__hip_bfloat16*)w;                 // 262144 B
    __hip_bfloat16* wv_t   = (__hip_bfloat16*)(w + 262144);      // 32768
    __hip_bfloat16* wg_t   = (__hip_bfloat16*)(w + 294912);      // 32768
    __hip_bfloat16* wab_t  = (__hip_bfloat16*)(w + 327680);      // 65536
    __hip_bfloat16* wo_t   = (__hip_bfloat16*)(w + 393216);      // 32768
    __hip_bfloat16* wo2_t  = (__hip_bfloat16*)(w + 425984);      // 32768
    float* normb           = (float*)(w + 458752);               // 262144
    float* wl              = (float*)(w + 720896);               // 2097152
    __hip_bfloat16* wlb    = (__hip_bfloat16*)(w + 2818048);     // 1048576
    char* bufA             = w + 3866624;                        // 67108864: a_t|b_t -> vb
    char* bufB             = w + 70975488;                       // 67108864: obuf

    __hip_bfloat16* a_t  = (__hip_bfloat16*)bufA;
    __hip_bfloat16* b_t  = a_t + 4194304;
    __hip_bfloat16* vb   = (__hip_bfloat16*)bufA;   // after k2
    __hip_bfloat16* obuf = (__hip_bfloat16*)bufB;

    k0_prep<<<896, 256, 0, stream>>>(opm_wout, pwa_wv, pwa_wg, tr_wa, tr_wb, pwa_wo, tr_wo,
                                     wout_t, wv_t, wg_t, wab_t, wo_t, wo2_t);
    k1_ab<<<2048, 256, 0, stream>>>(m, mask, opm_ln_w, opm_ln_b, opm_w1, opm_w2, a_t, b_t);
    k1b_norm<<<N, 256, 0, stream>>>(mask, normb);
    k2_opm<<<4096, 256, 0, stream>>>(a_t, b_t, wout_t, opm_bout, normb, z, z_out);
    k3_logits<<<N * N / 4, 256, 0, stream>>>(z_out, pwa_lnz_w, pwa_lnz_b, pwa_wz, wl);
    k4_softmax<<<N * H, 256, 0, stream>>>(wl, wlb);
    k5v<<<2048, 256, 0, stream>>>(m, pwa_lnm_w, pwa_lnm_b, wv_t, vb);
    k6a<<<2048, 256, 0, stream>>>(vb, wlb, obuf);
    k67<<<2048, 256, 0, stream>>>(m, pwa_lnm_w, pwa_lnm_b, wg_t, wo_t, obuf,
                                  tr_ln_w, tr_ln_b, wab_t, wo2_t, m_out);
}